// Round 10
// baseline (116330.408 us; speedup 1.0000x reference)
//
#include <hip/hip_runtime.h>
#include <hip/hip_cooperative_groups.h>
#include <math.h>

namespace cg = cooperative_groups;

#define NBLK 256
#define NTHR 1024
#define AG  __HIP_MEMORY_SCOPE_AGENT
#define SYS __HIP_MEMORY_SCOPE_SYSTEM

typedef float f4v __attribute__((ext_vector_type(4)));

// Problem sizes
constexpr int Bc = 32, Tc = 128, Ec = 512, Hc = 1024, Ac = 1024, Vc = 32000, Sc = 100;
constexpr long long OUT_ATTN = (long long)Sc * Bc * Vc;

// ---- workspace layout (floats) ----
constexpr long long O_ENCWIH = 0;
constexpr long long O_ENCWHH = O_ENCWIH + (long long)512 * 3072;
constexpr long long O_DECWIH = O_ENCWHH + (long long)1024 * 3072;
constexpr long long O_DECWHH = O_DECWIH + (long long)1536 * 3072;
constexpr long long O_ATTNWT = O_DECWHH + (long long)1024 * 3072;
constexpr long long O_CLSWT  = O_ATTNWT + (long long)2048 * 1024;
constexpr long long O_XENCT  = O_CLSWT + (long long)1024 * 32000;
constexpr long long O_GI     = O_XENCT + (long long)128 * 512 * 32;
constexpr long long O_ENCOUT = O_GI + (long long)128 * 32 * 3072;
constexpr long long O_H0     = O_ENCOUT + (long long)32 * 128 * 1024;  // enc h ping
constexpr long long O_H1     = O_H0 + 32768;                           // enc h pong
constexpr long long O_H2     = O_H1 + 32768;                           // decoder h
constexpr long long O_AVT    = O_H2 + 32768;                           // av^T
constexpr long long O_CTXT   = O_AVT + 32768;                          // context^T
constexpr long long O_PADEC  = O_CTXT + 32768;                         // [10][32][4096]
constexpr long long O_PAENC  = O_PADEC + (long long)10 * 32 * 4096;    // [8][32][3072]
constexpr long long O_PARGV  = O_PAENC + (long long)8 * 32 * 3072;     // [250][32]
constexpr long long O_PARGI  = O_PARGV + 8000;                         // [250][32] int
constexpr long long O_CNT    = O_PARGI + 8000;                         // int[1024] counters (encoder)
constexpr long long O_SLOT   = O_CNT + 1024;                           // int[1024] slot tags (decoder)
constexpr long long WS_FLOATS = O_SLOT + 1024;

// encoder counter indices (own 128B line each)
#define CI_H   128
#define CI_ENC 160   // + jc*32, jc<8

// decoder slot bases (int offsets into slot[])
#define SL_DA  0     // [240]
#define SL_DB  256   // [32]
#define SL_FIN 320   // [32]
#define SL_DD  384   // [250]

// sc0sc1 (cache-bypassing, coherence-point) loads for mutable cross-block data.
__device__ __forceinline__ float cohL(const float* p) { return __hip_atomic_load(p, __ATOMIC_RELAXED, SYS); }
__device__ __forceinline__ int   cohLi(const int* p) { return __hip_atomic_load(p, __ATOMIC_RELAXED, SYS); }

// Encoder primitives (r9-proven, unchanged)
__device__ __forceinline__ void spinw(int* c, int tgt, int tid) {
  if (tid == 0) {
    while (__hip_atomic_load(c, __ATOMIC_RELAXED, AG) < tgt)
      __builtin_amdgcn_s_sleep(4);
  }
  __syncthreads();
}
__device__ __forceinline__ void sigp(int* c, int tid) {
  __syncthreads();
  if (tid == 0) {
    __builtin_amdgcn_fence(__ATOMIC_RELEASE, "agent");
    atomicAdd(c, 1);
  }
}

// Decoder slot primitives: producer stores tag to OWN slot (after release fence);
// consumer polls N slots in parallel (thread i polls slot i). No RMW contention.
__device__ __forceinline__ void sigs(int* slotp, int tag, int tid) {
  __syncthreads();
  if (tid == 0) {
    __builtin_amdgcn_fence(__ATOMIC_RELEASE, "agent");
    __hip_atomic_store(slotp, tag, __ATOMIC_RELAXED, AG);
  }
}
__device__ __forceinline__ void pollN(const int* slots, int n, int tag, int tid) {
  if (tid < n) {
    while (__hip_atomic_load(&slots[tid], __ATOMIC_RELAXED, AG) < tag)
      __builtin_amdgcn_s_sleep(2);
  }
  __syncthreads();
}

__global__ __launch_bounds__(NTHR, 4) void seq2seq_kernel(
    const int* __restrict__ inp, const float* __restrict__ encEmb,
    const float* __restrict__ encWih, const float* __restrict__ encWhh,
    const float* __restrict__ encBih, const float* __restrict__ encBhh,
    const float* __restrict__ decEmb, const float* __restrict__ decWih,
    const float* __restrict__ decWhh, const float* __restrict__ decBih,
    const float* __restrict__ decBhh, const float* __restrict__ attnW,
    const float* __restrict__ attnB, const float* __restrict__ clsW,
    const float* __restrict__ clsB, float* __restrict__ out,
    float* __restrict__ ws)
{
  cg::grid_group grid = cg::this_grid();
  const int bid = blockIdx.x, tid = threadIdx.x;
  const long long gtid = (long long)bid * NTHR + tid;
  int* cnt  = (int*)(ws + O_CNT);
  int* slot = (int*)(ws + O_SLOT);

  __shared__ float smem[10624];
  int* sflag = (int*)(smem + 10600);
  int* nids  = (int*)(smem + 10368);

  // ======================= P0: transposes + gathers + zeros =======================
  {
    const int sg = tid >> 8, st = tid & 255;
    float* tile = smem + sg * 1056;
    const int c = st & 31, rr = st >> 5;
    for (int it = 0; it < 46; ++it) {
      int job = it * (NBLK * 4) + bid * 4 + sg;
      const float* src = nullptr; float* dst = nullptr;
      int R = 0, C = 0, tr = 0, tcd = 0;
      bool valid = true;
      int j = job;
      if (j < 1536)               { src = encWih; dst = ws + O_ENCWIH; R = 3072;  C = 512;  tr = j >> 4; tcd = j & 15; }
      else if ((j -= 1536) < 3072){ src = encWhh; dst = ws + O_ENCWHH; R = 3072;  C = 1024; tr = j >> 5; tcd = j & 31; }
      else if ((j -= 3072) < 4608){ src = decWih; dst = ws + O_DECWIH; R = 3072;  C = 1536; tr = j / 48; tcd = j % 48; }
      else if ((j -= 4608) < 3072){ src = decWhh; dst = ws + O_DECWHH; R = 3072;  C = 1024; tr = j >> 5; tcd = j & 31; }
      else if ((j -= 3072) < 2048){ src = attnW;  dst = ws + O_ATTNWT; R = 1024;  C = 2048; tr = j >> 6; tcd = j & 63; }
      else if ((j -= 2048) < 32000){src = clsW;   dst = ws + O_CLSWT;  R = 32000; C = 1024; tr = j >> 5; tcd = j & 31; }
      else valid = false;
      if (valid) {
        #pragma unroll
        for (int i = 0; i < 4; ++i) {
          int r = rr + (i << 3);
          tile[r * 33 + c] = src[(long long)(tr * 32 + r) * C + tcd * 32 + c];
        }
      }
      __syncthreads();
      if (valid) {
        #pragma unroll
        for (int i = 0; i < 4; ++i) {
          int c2 = rr + (i << 3);
          dst[(long long)(tcd * 32 + c2) * R + tr * 32 + c] = tile[c * 33 + c2];
        }
      }
      __syncthreads();
    }
  }
  for (long long i = gtid; i < (long long)128 * 512 * 32; i += (long long)NBLK * NTHR) {
    int b = (int)(i & 31);
    int k = (int)((i >> 5) & 511);
    int t = (int)(i >> 14);
    int row = inp[b * Tc + t];
    ws[O_XENCT + i] = encEmb[(long long)row * Ec + k];
  }
  for (long long i = gtid; i < 32768; i += (long long)NBLK * NTHR) {
    ws[O_H0 + i] = 0.f;
    ws[O_AVT + i] = 0.f;
  }
  grid.sync();

  // ======================= P1: Gi =======================
  for (int it = 0; it < 6; ++it) {
    int job = it * NBLK + bid;
    int t = job / 12, jc = job % 12;
    int jl = tid & 255, bq = tid >> 8;
    int j = jc * 256 + jl;
    float acc[8] = {0,0,0,0,0,0,0,0};
    const float* xb = ws + O_XENCT + (long long)t * 512 * 32 + bq * 8;
    const float* wb = ws + O_ENCWIH + j;
    for (int k = 0; k < 512; ++k) {
      float w = wb[(long long)k * 3072];
      float4 x0 = *(const float4*)(xb + k * 32);
      float4 x1 = *(const float4*)(xb + k * 32 + 4);
      acc[0] += x0.x * w; acc[1] += x0.y * w; acc[2] += x0.z * w; acc[3] += x0.w * w;
      acc[4] += x1.x * w; acc[5] += x1.y * w; acc[6] += x1.z * w; acc[7] += x1.w * w;
    }
    float bias = encBih[j];
    #pragma unroll
    for (int i = 0; i < 8; ++i) {
      int b = bq * 8 + i;
      __builtin_nontemporal_store(acc[i] + bias, &ws[O_GI + ((long long)t * 32 + b) * 3072 + j]);
    }
  }
  grid.sync();

  // ======================= P2: encoder GRU (verbatim r9) =======================
  if (bid < 192) {
    int g = bid / 64, rem = bid % 64;
    int jc = rem >> 3, kp = rem & 7;
    for (int t = 0; t < Tc; ++t) {
      long long RD = (t & 1) ? O_H1 : O_H0;
      long long WR = (t & 1) ? O_H0 : O_H1;
      spinw(cnt + CI_H, 8 * t, tid);
      {
        const float* hsrc = ws + RD + kp * 4096;
        #pragma unroll
        for (int r = 0; r < 4; ++r)
          smem[r * 1024 + tid] = cohL(hsrc + r * 1024 + tid);
      }
      __syncthreads();
      int jl = tid & 127, bq = tid >> 7;
      int col = g * 1024 + jc * 128 + jl;
      int b0 = bq * 4;
      float acc[4] = {0,0,0,0};
      const float* hb = smem + b0;
      const float* wb = ws + O_ENCWHH + (long long)(kp * 128) * 3072 + col;
      for (int k = 0; k < 128; ++k) {
        float w = wb[(long long)k * 3072];
        float4 x = *(const float4*)(hb + k * 32);
        acc[0] += x.x * w; acc[1] += x.y * w; acc[2] += x.z * w; acc[3] += x.w * w;
      }
      #pragma unroll
      for (int i = 0; i < 4; ++i)
        ws[O_PAENC + ((long long)(kp * 32) + b0 + i) * 3072 + col] = acc[i];
      __syncthreads();
      if (tid == 0) {
        __builtin_amdgcn_fence(__ATOMIC_RELEASE, "agent");
        int old = atomicAdd(cnt + CI_ENC + jc * 32, 1);
        *sflag = (old == 24 * (t + 1) - 1) ? 1 : 0;
      }
      __syncthreads();
      if (*sflag) {
        int fj = tid & 127, fq = tid >> 7;
        int j = jc * 128 + fj;
        #pragma unroll
        for (int i = 0; i < 4; ++i) {
          int b = fq * 4 + i;
          float gr = 0, gz = 0, gn = 0;
          #pragma unroll
          for (int kp2 = 0; kp2 < 8; ++kp2) {
            long long base = O_PAENC + ((long long)(kp2 * 32) + b) * 3072;
            gr += cohL(&ws[base + j]);
            gz += cohL(&ws[base + 1024 + j]);
            gn += cohL(&ws[base + 2048 + j]);
          }
          long long gib = O_GI + ((long long)t * 32 + b) * 3072;
          float gir = ws[gib + j], giz = ws[gib + 1024 + j], gin = ws[gib + 2048 + j];
          float r = 1.f / (1.f + expf(-(gir + gr + encBhh[j])));
          float z = 1.f / (1.f + expf(-(giz + gz + encBhh[1024 + j])));
          float n = tanhf(gin + r * (gn + encBhh[2048 + j]));
          float hold = cohL(&ws[RD + (long long)j * 32 + b]);
          float hn = (1.f - z) * n + z * hold;
          ws[WR + (long long)j * 32 + b] = hn;
          ws[O_ENCOUT + ((long long)b * 128 + t) * 1024 + j] = hn;
          if (t == Tc - 1) ws[O_H2 + (long long)j * 32 + b] = hn;
        }
        sigp(cnt + CI_H, tid);
      }
      __syncthreads();
    }
  }

  // ======================= P3: decoder, slot-signaled dataflow =======================
  for (int s = 0; s < Sc; ++s) {
    // ---- DA (240 blocks) ----
    if (bid < 240) {
      int gate, loc;
      if (bid < 80)       { gate = 0; loc = bid; }
      else if (bid < 160) { gate = 1; loc = bid - 80; }
      else if (bid < 208) { gate = 2; loc = bid - 160; }
      else                { gate = 3; loc = bid - 208; }
      int nkp = (gate < 2) ? 10 : ((gate == 2) ? 6 : 4);
      int jc = loc / nkp, kp = loc % nkp;
      int kg = (gate == 3 ? 1536 : 0) + kp * 256;
      bool embp = (kg < 512);
      if (s == 0) {
        spinw(cnt + CI_H, 8 * Tc, tid); // encoder fully done
        if (tid < 32) nids[tid] = 0;
        __syncthreads();
      } else if (embp) {
        pollN(slot + SL_DD, 250, s, tid);
        // argmax over 250 partials via coh reads (semilattice: order-free)
        float* pv = smem; int* pi = (int*)(smem + 1024);
        int b = tid & 31, ch = tid >> 5;
        float bv = -3.4e38f; int bi = 0;
        for (int r = ch; r < 250; r += 32) {
          float v = cohL(&ws[O_PARGV + r * 32 + b]);
          int ix = cohLi(((int*)(ws + O_PARGI)) + r * 32 + b);
          if (v > bv || (v == bv && ix < bi)) { bv = v; bi = ix; }
        }
        pv[ch * 32 + b] = bv; pi[ch * 32 + b] = bi;
        __syncthreads();
        if (tid < 32) {
          float bb = -3.4e38f; int bbi = 0;
          for (int c2 = 0; c2 < 32; ++c2) {
            float v = pv[c2 * 32 + tid]; int ix = pi[c2 * 32 + tid];
            if (v > bb || (v == bb && ix < bbi)) { bb = v; bbi = ix; }
          }
          nids[tid] = bbi;
        }
        __syncthreads();
      } else if (kg >= 1536) {
        pollN(slot + SL_DB, 32, s, tid);   // h2(s-1) ready
      } else {
        pollN(slot + SL_FIN, 32, s, tid);  // av(s-1) ready
      }
      // DA body (verbatim r9 arithmetic)
      int jl = tid & 127, bq = tid >> 7;
      int b0 = bq * 4;
      int jcol = jc * 128 + jl;
      int wcol = (gate >= 2 ? 2048 : gate * 1024) + jcol;
      const float* wb = (kg < 1536) ? (ws + O_DECWIH + (long long)kg * 3072 + wcol)
                                    : (ws + O_DECWHH + (long long)(kg - 1536) * 3072 + wcol);
      float acc[4] = {0,0,0,0};
      if (embp) {
        const float* e0 = decEmb + (long long)nids[b0    ] * 512 + kg;
        const float* e1 = decEmb + (long long)nids[b0 + 1] * 512 + kg;
        const float* e2 = decEmb + (long long)nids[b0 + 2] * 512 + kg;
        const float* e3 = decEmb + (long long)nids[b0 + 3] * 512 + kg;
        for (int k = 0; k < 256; ++k) {
          float w = wb[(long long)k * 3072];
          acc[0] += e0[k] * w; acc[1] += e1[k] * w; acc[2] += e2[k] * w; acc[3] += e3[k] * w;
        }
      } else {
        const float* src = (kg < 1536) ? (ws + O_AVT + (long long)(kg - 512) * 32)
                                       : (ws + O_H2 + (long long)(kg - 1536) * 32);
        #pragma unroll
        for (int r = 0; r < 8; ++r)
          smem[r * 1024 + tid] = cohL(src + r * 1024 + tid);
        __syncthreads();
        const float* xb = smem + b0;
        for (int k = 0; k < 256; ++k) {
          float w = wb[(long long)k * 3072];
          float4 x = *(const float4*)(xb + k * 32);
          acc[0] += x.x * w; acc[1] += x.y * w; acc[2] += x.z * w; acc[3] += x.w * w;
        }
      }
      int colout = gate * 1024 + jcol;
      #pragma unroll
      for (int i = 0; i < 4; ++i)
        ws[O_PADEC + ((long long)(kp * 32) + b0 + i) * 4096 + colout] = acc[i];
      sigs(slot + SL_DA + bid, s + 1, tid);
    }

    // ---- DB: gates finalize + attention + context (32 blocks) ----
    if (bid < 32) {
      pollN(slot + SL_DA, 240, s + 1, tid);
      int b = bid;
      float* h2l = smem;
      float* scl = smem + 1024;
      float* wl  = smem + 1152;
      float* red = smem + 1280;
      {
        int j = tid;
        float gr = 0, gz = 0, gin = 0, ghn = 0;
        #pragma unroll
        for (int kp = 0; kp < 10; ++kp) {
          long long base = O_PADEC + ((long long)(kp * 32) + b) * 4096;
          gr += cohL(&ws[base + j]);
          gz += cohL(&ws[base + 1024 + j]);
          if (kp < 6) gin += cohL(&ws[base + 2048 + j]);
          if (kp < 4) ghn += cohL(&ws[base + 3072 + j]);
        }
        float r = 1.f / (1.f + expf(-(gr + decBih[j] + decBhh[j])));
        float z = 1.f / (1.f + expf(-(gz + decBih[1024 + j] + decBhh[1024 + j])));
        float n = tanhf(gin + decBih[2048 + j] + r * (ghn + decBhh[2048 + j]));
        float hold = ws[O_H2 + (long long)j * 32 + b]; // own bytes
        float h2 = (1.f - z) * n + z * hold;
        ws[O_H2 + (long long)j * 32 + b] = h2;
        h2l[j] = h2;
      }
      __syncthreads();
      { // scores
        int wv = tid >> 6, lane = tid & 63;
        float h2v[16];
        #pragma unroll
        for (int i = 0; i < 16; ++i) h2v[i] = h2l[lane + (i << 6)];
        for (int t8 = 0; t8 < 8; ++t8) {
          int tt = wv * 8 + t8;
          const float* eo = ws + O_ENCOUT + ((long long)b * 128 + tt) * 1024 + lane;
          float a = 0;
          #pragma unroll
          for (int i = 0; i < 16; ++i) a += eo[i << 6] * h2v[i];
          #pragma unroll
          for (int off = 32; off; off >>= 1) a += __shfl_xor(a, off, 64);
          if (lane == 0) scl[tt] = a;
        }
      }
      __syncthreads();
      { // softmax over 128
        float v = 0, m = -3.4e38f;
        if (tid < 128) {
          v = scl[tid]; m = v;
          #pragma unroll
          for (int off = 32; off; off >>= 1) m = fmaxf(m, __shfl_xor(m, off, 64));
          if ((tid & 63) == 0) red[tid >> 6] = m;
        }
        __syncthreads();
        float mm = fmaxf(red[0], red[1]);
        float e = 0.f;
        if (tid < 128) {
          e = expf(v - mm);
          float se = e;
          #pragma unroll
          for (int off = 32; off; off >>= 1) se += __shfl_xor(se, off, 64);
          if ((tid & 63) == 0) red[2 + (tid >> 6)] = se;
        }
        __syncthreads();
        if (tid < 128) {
          float wgt = e / (red[2] + red[3]);
          wl[tid] = wgt;
          __builtin_nontemporal_store(wgt, &out[OUT_ATTN + ((long long)s * 32 + b) * 128 + tid]);
        }
      }
      __syncthreads();
      { // context
        int j = tid;
        float a = 0;
        const float* eo = ws + O_ENCOUT + (long long)b * 128 * 1024 + j;
        for (int tt = 0; tt < 128; ++tt) a += wl[tt] * eo[(long long)tt * 1024];
        ws[O_CTXT + (long long)j * 32 + b] = a;
      }
      sigs(slot + SL_DB + bid, s + 1, tid);
    }

    // ---- DC: av direct (32 blocks), exact r9 chunk order ----
    if (bid < 32) {
      pollN(slot + SL_DB, 32, s + 1, tid);
      int jf = tid >> 5, b = tid & 31;
      int j = (bid << 5) + jf;
      float sum = 0.f;
      #pragma unroll 1
      for (int kp = 0; kp < 16; ++kp) {
        int kk0 = kp * 128;
        const float* src = (kk0 < 1024) ? (ws + O_CTXT + (long long)kk0 * 32)
                                        : (ws + O_H2 + (long long)(kk0 - 1024) * 32);
        #pragma unroll
        for (int r = 0; r < 4; ++r)
          smem[r * 1024 + tid] = cohL(src + r * 1024 + tid);
        __syncthreads();
        const float* wk = ws + O_ATTNWT + (long long)kk0 * 1024 + j;
        float pp = 0.f;
        for (int k = 0; k < 128; ++k)
          pp += smem[k * 32 + b] * wk[(long long)k * 1024];
        sum += pp;
        __syncthreads();
      }
      ws[O_AVT + (long long)j * 32 + b] = tanhf(sum + attnB[j]);
      sigs(slot + SL_FIN + bid, s + 1, tid);
    }

    // ---- DD: classifier + argmax partials (250 blocks) ----
    if (bid < 250) {
      pollN(slot + SL_FIN, 32, s + 1, tid);
      float* wc  = smem;        // [64][128] staged cls weights
      float* sav = smem + 8192; // [64][32] staged av chunk
      int jl = tid & 127, bg = tid >> 7;
      int b0 = bg * 4;
      int j = bid * 128 + jl;
      float acc[4] = {0,0,0,0};
      for (int kc = 0; kc < 1024; kc += 64) {
        #pragma unroll
        for (int i = 0; i < 2; ++i) {
          int t4 = tid + i * 1024;
          int kk = t4 >> 5, c4 = t4 & 31;
          *(f4v*)(wc + kk * 128 + c4 * 4) =
            *(const f4v*)(ws + O_CLSWT + (long long)(kc + kk) * 32000 + bid * 128 + c4 * 4);
        }
        #pragma unroll
        for (int i = 0; i < 2; ++i)
          sav[i * 1024 + tid] = cohL(ws + O_AVT + (long long)kc * 32 + i * 1024 + tid);
        __syncthreads();
        for (int k = 0; k < 64; ++k) {
          float w = wc[k * 128 + jl];
          float4 a = *(const float4*)(sav + k * 32 + b0);
          acc[0] += a.x * w; acc[1] += a.y * w; acc[2] += a.z * w; acc[3] += a.w * w;
        }
        __syncthreads();
      }
      float cb = clsB[j];
      float pvv[4];
      #pragma unroll
      for (int i = 0; i < 4; ++i) {
        pvv[i] = acc[i] + cb;
        __builtin_nontemporal_store(pvv[i], &out[((long long)s * 32 + b0 + i) * 32000 + j]);
      }
      float* lv = smem;
      int*   li = (int*)(smem + 4096);
      __syncthreads();
      #pragma unroll
      for (int i = 0; i < 4; ++i) {
        lv[(b0 + i) * 128 + jl] = pvv[i];
        li[(b0 + i) * 128 + jl] = j;
      }
      __syncthreads();
      float* l2v = smem + 8192;
      int*   l2i = (int*)(smem + 9216);
      {
        int b = tid >> 5, r = tid & 31;
        float bv = -3.4e38f; int bi2 = 0;
        #pragma unroll
        for (int i = 0; i < 4; ++i) {
          float v = lv[b * 128 + r + (i << 5)];
          int ix = li[b * 128 + r + (i << 5)];
          if (v > bv || (v == bv && ix < bi2)) { bv = v; bi2 = ix; }
        }
        l2v[b * 32 + r] = bv; l2i[b * 32 + r] = bi2;
      }
      __syncthreads();
      if (tid < 32) {
        float bv = -3.4e38f; int bi2 = 0;
        for (int r = 0; r < 32; ++r) {
          float v = l2v[tid * 32 + r]; int ix = l2i[tid * 32 + r];
          if (v > bv || (v == bv && ix < bi2)) { bv = v; bi2 = ix; }
        }
        ws[O_PARGV + bid * 32 + tid] = bv;
        ((int*)(ws + O_PARGI))[bid * 32 + tid] = bi2;
      }
      sigs(slot + SL_DD + bid, s + 1, tid);
    }
  }
}

extern "C" void kernel_launch(void* const* d_in, const int* in_sizes, int n_in,
                              void* d_out, int out_size, void* d_ws, size_t ws_size,
                              hipStream_t stream) {
  const int*   inp    = (const int*)  d_in[0];
  const float* encEmb = (const float*)d_in[1];
  const float* encWih = (const float*)d_in[2];
  const float* encWhh = (const float*)d_in[3];
  const float* encBih = (const float*)d_in[4];
  const float* encBhh = (const float*)d_in[5];
  const float* decEmb = (const float*)d_in[6];
  const float* decWih = (const float*)d_in[7];
  const float* decWhh = (const float*)d_in[8];
  const float* decBih = (const float*)d_in[9];
  const float* decBhh = (const float*)d_in[10];
  const float* attnW  = (const float*)d_in[11];
  const float* attnB  = (const float*)d_in[12];
  const float* clsW   = (const float*)d_in[13];
  const float* clsB   = (const float*)d_in[14];
  float* out = (float*)d_out;
  float* ws  = (float*)d_ws;

  if (ws_size < (size_t)WS_FLOATS * sizeof(float)) return;

  // zero counters + slots each launch (graph memset node, ordered before kernel)
  (void)hipMemsetAsync(ws + O_CNT, 0, 2048 * sizeof(int), stream);

  void* args[] = { &inp, &encEmb, &encWih, &encWhh, &encBih, &encBhh,
                   &decEmb, &decWih, &decWhh, &decBih, &decBhh,
                   &attnW, &attnB, &clsW, &clsB, &out, &ws };
  (void)hipLaunchCooperativeKernel((void*)seq2seq_kernel, dim3(NBLK), dim3(NTHR),
                                   args, 0, stream);
}

// Round 11
// 113534.546 us; speedup vs baseline: 1.0246x; 1.0246x over previous
//
#include <hip/hip_runtime.h>
#include <hip/hip_cooperative_groups.h>
#include <math.h>

namespace cg = cooperative_groups;

#define NBLK 256
#define NTHR 1024
#define AG  __HIP_MEMORY_SCOPE_AGENT
#define SYS __HIP_MEMORY_SCOPE_SYSTEM

typedef float f4v __attribute__((ext_vector_type(4)));

// Problem sizes
constexpr int Bc = 32, Tc = 128, Ec = 512, Hc = 1024, Ac = 1024, Vc = 32000, Sc = 100;
constexpr long long OUT_ATTN = (long long)Sc * Bc * Vc;

// ---- workspace layout (floats) ----
constexpr long long O_ENCWIH = 0;
constexpr long long O_ENCWHH = O_ENCWIH + (long long)512 * 3072;
constexpr long long O_DECWIH = O_ENCWHH + (long long)1024 * 3072;
constexpr long long O_DECWHH = O_DECWIH + (long long)1536 * 3072;
constexpr long long O_ATTNWT = O_DECWHH + (long long)1024 * 3072;
constexpr long long O_CLSWT  = O_ATTNWT + (long long)2048 * 1024;
constexpr long long O_XENCT  = O_CLSWT + (long long)1024 * 32000;
constexpr long long O_GI     = O_XENCT + (long long)128 * 512 * 32;
constexpr long long O_ENCOUT = O_GI + (long long)128 * 32 * 3072;
constexpr long long O_H0     = O_ENCOUT + (long long)32 * 128 * 1024;  // enc h ping
constexpr long long O_H1     = O_H0 + 32768;                           // enc h pong
constexpr long long O_H2     = O_H1 + 32768;                           // decoder h
constexpr long long O_AVT    = O_H2 + 32768;                           // av^T
constexpr long long O_CTXT   = O_AVT + 32768;                          // context^T
constexpr long long O_PADEC  = O_CTXT + 32768;                         // [10][32][4096]
constexpr long long O_PAENC  = O_PADEC + (long long)10 * 32 * 4096;    // [8][32][3072]
constexpr long long O_PARGV  = O_PAENC + (long long)8 * 32 * 3072;     // [250][32]
constexpr long long O_PARGI  = O_PARGV + 8000;                         // [250][32] int
constexpr long long O_CNT    = O_PARGI + 8000;                         // int[2048] arrival counters
constexpr long long O_GO     = O_CNT + 2048;                           // int[5*8192] private go-lines
constexpr long long WS_FLOATS = O_GO + 5 * 8192;

// arrival counter lines (int offsets in cnt[]; one 128B line each)
#define CI_H    128
#define CI_ENC  160   // + jc*32, jc<8
#define SUB_DA  512   // + (bid&15)*32
#define SUB_DB  1024  // + (bid&7)*32
#define SUB_FIN 1280  // + (bid&7)*32
#define SUB_DD  1536  // + (bid&15)*32

// go arrays (int offsets in go[]; per-block private line = idx*32)
#define GO_ENC  0
#define GO_DA   8192
#define GO_DB   16384
#define GO_DC   24576
#define GO_DD   32768

// sc0sc1 (cache-bypassing, coherence-point) loads for mutable cross-block data.
__device__ __forceinline__ float cohL(const float* p) { return __hip_atomic_load(p, __ATOMIC_RELAXED, SYS); }
__device__ __forceinline__ int   cohLi(const int* p) { return __hip_atomic_load(p, __ATOMIC_RELAXED, SYS); }

// Consumer: tid0 polls this block's PRIVATE go line (no line sharing anywhere).
__device__ __forceinline__ void waitgo(const int* g, int tag, int tid) {
  if (tid == 0) {
    while (__hip_atomic_load(g, __ATOMIC_RELAXED, AG) < tag)
      __builtin_amdgcn_s_sleep(2);
  }
  __syncthreads();
}
// Producer arrival: r9-proven (syncthreads -> tid0 release fence (wbl2) -> RMW on spread line).
__device__ __forceinline__ void siga(int* line, int tid) {
  __syncthreads();
  if (tid == 0) {
    __builtin_amdgcn_fence(__ATOMIC_RELEASE, "agent");
    atomicAdd(line, 1);
  }
}
// Relay-only poll of arrival sub-lines (<=16 threads, sole pollers of these lines).
__device__ __forceinline__ void rpoll(const int* base, int n, int tgt, int tid) {
  if (tid < n) {
    while (__hip_atomic_load(base + tid * 32, __ATOMIC_RELAXED, AG) < tgt)
      __builtin_amdgcn_s_sleep(1);
  }
  __syncthreads();
  asm volatile("" ::: "memory");
}
__device__ __forceinline__ void gostore(int* g, int tag) {
  __hip_atomic_store(g, tag, __ATOMIC_RELAXED, AG);
}
// DA block class: 0=emb (needs DD(s-1)), 1=av (needs FIN(s-1)), 2=h2 (needs DB(s-1))
__device__ __forceinline__ int da_class(int t) {
  int gate, loc;
  if (t < 80)       { gate = 0; loc = t; }
  else if (t < 160) { gate = 1; loc = t - 80; }
  else if (t < 208) { gate = 2; loc = t - 160; }
  else              { gate = 3; loc = t - 208; }
  int nkp = (gate < 2) ? 10 : ((gate == 2) ? 6 : 4);
  int kp = loc % nkp;
  int kg = (gate == 3 ? 1536 : 0) + kp * 256;
  return (kg < 512) ? 0 : (kg < 1536 ? 1 : 2);
}

__global__ __launch_bounds__(NTHR, 4) void seq2seq_kernel(
    const int* __restrict__ inp, const float* __restrict__ encEmb,
    const float* __restrict__ encWih, const float* __restrict__ encWhh,
    const float* __restrict__ encBih, const float* __restrict__ encBhh,
    const float* __restrict__ decEmb, const float* __restrict__ decWih,
    const float* __restrict__ decWhh, const float* __restrict__ decBih,
    const float* __restrict__ decBhh, const float* __restrict__ attnW,
    const float* __restrict__ attnB, const float* __restrict__ clsW,
    const float* __restrict__ clsB, float* __restrict__ out,
    float* __restrict__ ws)
{
  cg::grid_group grid = cg::this_grid();
  const int bid = blockIdx.x, tid = threadIdx.x;
  const long long gtid = (long long)bid * NTHR + tid;
  int* cnt = (int*)(ws + O_CNT);
  int* go  = (int*)(ws + O_GO);

  __shared__ float smem[10624];
  int* sflag = (int*)(smem + 10600);
  int* nids  = (int*)(smem + 10368);

  // ======================= P0: transposes + gathers + zeros =======================
  {
    const int sg = tid >> 8, st = tid & 255;
    float* tile = smem + sg * 1056;
    const int c = st & 31, rr = st >> 5;
    for (int it = 0; it < 46; ++it) {
      int job = it * (NBLK * 4) + bid * 4 + sg;
      const float* src = nullptr; float* dst = nullptr;
      int R = 0, C = 0, tr = 0, tcd = 0;
      bool valid = true;
      int j = job;
      if (j < 1536)               { src = encWih; dst = ws + O_ENCWIH; R = 3072;  C = 512;  tr = j >> 4; tcd = j & 15; }
      else if ((j -= 1536) < 3072){ src = encWhh; dst = ws + O_ENCWHH; R = 3072;  C = 1024; tr = j >> 5; tcd = j & 31; }
      else if ((j -= 3072) < 4608){ src = decWih; dst = ws + O_DECWIH; R = 3072;  C = 1536; tr = j / 48; tcd = j % 48; }
      else if ((j -= 4608) < 3072){ src = decWhh; dst = ws + O_DECWHH; R = 3072;  C = 1024; tr = j >> 5; tcd = j & 31; }
      else if ((j -= 3072) < 2048){ src = attnW;  dst = ws + O_ATTNWT; R = 1024;  C = 2048; tr = j >> 6; tcd = j & 63; }
      else if ((j -= 2048) < 32000){src = clsW;   dst = ws + O_CLSWT;  R = 32000; C = 1024; tr = j >> 5; tcd = j & 31; }
      else valid = false;
      if (valid) {
        #pragma unroll
        for (int i = 0; i < 4; ++i) {
          int r = rr + (i << 3);
          tile[r * 33 + c] = src[(long long)(tr * 32 + r) * C + tcd * 32 + c];
        }
      }
      __syncthreads();
      if (valid) {
        #pragma unroll
        for (int i = 0; i < 4; ++i) {
          int c2 = rr + (i << 3);
          dst[(long long)(tcd * 32 + c2) * R + tr * 32 + c] = tile[c * 33 + c2];
        }
      }
      __syncthreads();
    }
  }
  for (long long i = gtid; i < (long long)128 * 512 * 32; i += (long long)NBLK * NTHR) {
    int b = (int)(i & 31);
    int k = (int)((i >> 5) & 511);
    int t = (int)(i >> 14);
    int row = inp[b * Tc + t];
    ws[O_XENCT + i] = encEmb[(long long)row * Ec + k];
  }
  for (long long i = gtid; i < 32768; i += (long long)NBLK * NTHR) {
    ws[O_H0 + i] = 0.f;
    ws[O_AVT + i] = 0.f;
  }
  grid.sync();

  // ======================= P1: Gi =======================
  for (int it = 0; it < 6; ++it) {
    int job = it * NBLK + bid;
    int t = job / 12, jc = job % 12;
    int jl = tid & 255, bq = tid >> 8;
    int j = jc * 256 + jl;
    float acc[8] = {0,0,0,0,0,0,0,0};
    const float* xb = ws + O_XENCT + (long long)t * 512 * 32 + bq * 8;
    const float* wb = ws + O_ENCWIH + j;
    for (int k = 0; k < 512; ++k) {
      float w = wb[(long long)k * 3072];
      float4 x0 = *(const float4*)(xb + k * 32);
      float4 x1 = *(const float4*)(xb + k * 32 + 4);
      acc[0] += x0.x * w; acc[1] += x0.y * w; acc[2] += x0.z * w; acc[3] += x0.w * w;
      acc[4] += x1.x * w; acc[5] += x1.y * w; acc[6] += x1.z * w; acc[7] += x1.w * w;
    }
    float bias = encBih[j];
    #pragma unroll
    for (int i = 0; i < 8; ++i) {
      int b = bq * 8 + i;
      __builtin_nontemporal_store(acc[i] + bias, &ws[O_GI + ((long long)t * 32 + b) * 3072 + j]);
    }
  }
  grid.sync();

  // ======================= P2: encoder GRU (r9 arithmetic; relay-signaled) =======================
  if (bid < 192) {
    int g = bid / 64, rem = bid % 64;
    int jc = rem >> 3, kp = rem & 7;
    for (int t = 0; t < Tc; ++t) {
      long long RD = (t & 1) ? O_H1 : O_H0;
      long long WR = (t & 1) ? O_H0 : O_H1;
      waitgo(go + GO_ENC + bid * 32, t, tid); // h(t) ready (tag t written after CI_H>=8t)
      {
        const float* hsrc = ws + RD + kp * 4096;
        #pragma unroll
        for (int r = 0; r < 4; ++r)
          smem[r * 1024 + tid] = cohL(hsrc + r * 1024 + tid);
      }
      __syncthreads();
      int jl = tid & 127, bq = tid >> 7;
      int col = g * 1024 + jc * 128 + jl;
      int b0 = bq * 4;
      float acc[4] = {0,0,0,0};
      const float* hb = smem + b0;
      const float* wb = ws + O_ENCWHH + (long long)(kp * 128) * 3072 + col;
      for (int k = 0; k < 128; ++k) {
        float w = wb[(long long)k * 3072];
        float4 x = *(const float4*)(hb + k * 32);
        acc[0] += x.x * w; acc[1] += x.y * w; acc[2] += x.z * w; acc[3] += x.w * w;
      }
      #pragma unroll
      for (int i = 0; i < 4; ++i)
        ws[O_PAENC + ((long long)(kp * 32) + b0 + i) * 3072 + col] = acc[i];
      __syncthreads();
      if (tid == 0) {
        __builtin_amdgcn_fence(__ATOMIC_RELEASE, "agent");
        int old = atomicAdd(cnt + CI_ENC + jc * 32, 1);
        *sflag = (old == 24 * (t + 1) - 1) ? 1 : 0;
      }
      __syncthreads();
      if (*sflag) { // last arriver: E2 finalize for this jc
        int fj = tid & 127, fq = tid >> 7;
        int j = jc * 128 + fj;
        #pragma unroll
        for (int i = 0; i < 4; ++i) {
          int b = fq * 4 + i;
          float gr = 0, gz = 0, gn = 0;
          #pragma unroll
          for (int kp2 = 0; kp2 < 8; ++kp2) {
            long long base = O_PAENC + ((long long)(kp2 * 32) + b) * 3072;
            gr += cohL(&ws[base + j]);
            gz += cohL(&ws[base + 1024 + j]);
            gn += cohL(&ws[base + 2048 + j]);
          }
          long long gib = O_GI + ((long long)t * 32 + b) * 3072;
          float gir = ws[gib + j], giz = ws[gib + 1024 + j], gin = ws[gib + 2048 + j];
          float r = 1.f / (1.f + expf(-(gir + gr + encBhh[j])));
          float z = 1.f / (1.f + expf(-(giz + gz + encBhh[1024 + j])));
          float n = tanhf(gin + r * (gn + encBhh[2048 + j]));
          float hold = cohL(&ws[RD + (long long)j * 32 + b]);
          float hn = (1.f - z) * n + z * hold;
          ws[WR + (long long)j * 32 + b] = hn;
          ws[O_ENCOUT + ((long long)b * 128 + t) * 1024 + j] = hn;
          if (t == Tc - 1) ws[O_H2 + (long long)j * 32 + b] = hn;
        }
        __syncthreads();
        if (tid == 0) {
          __builtin_amdgcn_fence(__ATOMIC_RELEASE, "agent");
          atomicAdd(cnt + CI_H, 1);
        }
      }
      __syncthreads();
    }
  } else if (bid == 255) {
    // ======================= RELAY: sole poller of arrival lines; broadcasts go-tags =======================
    const int myclass = (tid < 240) ? da_class(tid) : -1;
    // encoder relay
    for (int t = 0; t < Tc; ++t) {
      if (tid == 0) {
        while (__hip_atomic_load(cnt + CI_H, __ATOMIC_RELAXED, AG) < 8 * (t + 1))
          __builtin_amdgcn_s_sleep(1);
      }
      __syncthreads();
      asm volatile("" ::: "memory");
      if (tid < 192) gostore(go + GO_ENC + tid * 32, t + 1);
      __syncthreads();
    }
    // encoder done -> DA(0)
    if (tid < 240) gostore(go + GO_DA + tid * 32, 1);
    __syncthreads();
    // decoder relay
    for (int s = 0; s < Sc; ++s) {
      rpoll(cnt + SUB_DA, 16, 15 * (s + 1), tid);
      if (tid < 32) gostore(go + GO_DB + tid * 32, s + 1);
      rpoll(cnt + SUB_DB, 8, 4 * (s + 1), tid);
      if (tid < 32) gostore(go + GO_DC + tid * 32, s + 1);
      if (myclass == 2) gostore(go + GO_DA + tid * 32, s + 2);
      rpoll(cnt + SUB_FIN, 8, 4 * (s + 1), tid);
      if (tid < 250) gostore(go + GO_DD + tid * 32, s + 1);
      if (myclass == 1) gostore(go + GO_DA + tid * 32, s + 2);
      if (tid < 16) {
        int tgt = ((tid < 10) ? 16 : 15) * (s + 1);
        while (__hip_atomic_load(cnt + SUB_DD + tid * 32, __ATOMIC_RELAXED, AG) < tgt)
          __builtin_amdgcn_s_sleep(1);
      }
      __syncthreads();
      asm volatile("" ::: "memory");
      if (myclass == 0) gostore(go + GO_DA + tid * 32, s + 2);
      __syncthreads();
    }
  }

  // ======================= P3: decoder, relay-signaled dataflow =======================
  if (bid != 255) {
    for (int s = 0; s < Sc; ++s) {
      // ---- DA (240 blocks) ----
      if (bid < 240) {
        int gate, loc;
        if (bid < 80)       { gate = 0; loc = bid; }
        else if (bid < 160) { gate = 1; loc = bid - 80; }
        else if (bid < 208) { gate = 2; loc = bid - 160; }
        else                { gate = 3; loc = bid - 208; }
        int nkp = (gate < 2) ? 10 : ((gate == 2) ? 6 : 4);
        int jc = loc / nkp, kp = loc % nkp;
        int kg = (gate == 3 ? 1536 : 0) + kp * 256;
        bool embp = (kg < 512);
        waitgo(go + GO_DA + bid * 32, s + 1, tid);
        if (embp) {
          if (s == 0) {
            if (tid < 32) nids[tid] = 0;
            __syncthreads();
          } else {
            // argmax over 250 partials via coh reads (semilattice: order-free)
            float* pv = smem; int* pi = (int*)(smem + 1024);
            int b = tid & 31, ch = tid >> 5;
            float bv = -3.4e38f; int bi = 0;
            for (int r = ch; r < 250; r += 32) {
              float v = cohL(&ws[O_PARGV + r * 32 + b]);
              int ix = cohLi(((int*)(ws + O_PARGI)) + r * 32 + b);
              if (v > bv || (v == bv && ix < bi)) { bv = v; bi = ix; }
            }
            pv[ch * 32 + b] = bv; pi[ch * 32 + b] = bi;
            __syncthreads();
            if (tid < 32) {
              float bb = -3.4e38f; int bbi = 0;
              for (int c2 = 0; c2 < 32; ++c2) {
                float v = pv[c2 * 32 + tid]; int ix = pi[c2 * 32 + tid];
                if (v > bb || (v == bb && ix < bbi)) { bb = v; bbi = ix; }
              }
              nids[tid] = bbi;
            }
            __syncthreads();
          }
        }
        // DA body (verbatim r9/r10 arithmetic)
        int jl = tid & 127, bq = tid >> 7;
        int b0 = bq * 4;
        int jcol = jc * 128 + jl;
        int wcol = (gate >= 2 ? 2048 : gate * 1024) + jcol;
        const float* wb = (kg < 1536) ? (ws + O_DECWIH + (long long)kg * 3072 + wcol)
                                      : (ws + O_DECWHH + (long long)(kg - 1536) * 3072 + wcol);
        float acc[4] = {0,0,0,0};
        if (embp) {
          const float* e0 = decEmb + (long long)nids[b0    ] * 512 + kg;
          const float* e1 = decEmb + (long long)nids[b0 + 1] * 512 + kg;
          const float* e2 = decEmb + (long long)nids[b0 + 2] * 512 + kg;
          const float* e3 = decEmb + (long long)nids[b0 + 3] * 512 + kg;
          for (int k = 0; k < 256; ++k) {
            float w = wb[(long long)k * 3072];
            acc[0] += e0[k] * w; acc[1] += e1[k] * w; acc[2] += e2[k] * w; acc[3] += e3[k] * w;
          }
        } else {
          const float* src = (kg < 1536) ? (ws + O_AVT + (long long)(kg - 512) * 32)
                                         : (ws + O_H2 + (long long)(kg - 1536) * 32);
          #pragma unroll
          for (int r = 0; r < 8; ++r)
            smem[r * 1024 + tid] = cohL(src + r * 1024 + tid);
          __syncthreads();
          const float* xb = smem + b0;
          for (int k = 0; k < 256; ++k) {
            float w = wb[(long long)k * 3072];
            float4 x = *(const float4*)(xb + k * 32);
            acc[0] += x.x * w; acc[1] += x.y * w; acc[2] += x.z * w; acc[3] += x.w * w;
          }
        }
        int colout = gate * 1024 + jcol;
        #pragma unroll
        for (int i = 0; i < 4; ++i)
          ws[O_PADEC + ((long long)(kp * 32) + b0 + i) * 4096 + colout] = acc[i];
        siga(cnt + SUB_DA + (bid & 15) * 32, tid);
      }

      // ---- DB: gates finalize + attention + context (32 blocks) ----
      if (bid < 32) {
        waitgo(go + GO_DB + bid * 32, s + 1, tid);
        int b = bid;
        float* h2l = smem;
        float* scl = smem + 1024;
        float* wl  = smem + 1152;
        float* red = smem + 1280;
        {
          int j = tid;
          float gr = 0, gz = 0, gin = 0, ghn = 0;
          #pragma unroll
          for (int kp = 0; kp < 10; ++kp) {
            long long base = O_PADEC + ((long long)(kp * 32) + b) * 4096;
            gr += cohL(&ws[base + j]);
            gz += cohL(&ws[base + 1024 + j]);
            if (kp < 6) gin += cohL(&ws[base + 2048 + j]);
            if (kp < 4) ghn += cohL(&ws[base + 3072 + j]);
          }
          float r = 1.f / (1.f + expf(-(gr + decBih[j] + decBhh[j])));
          float z = 1.f / (1.f + expf(-(gz + decBih[1024 + j] + decBhh[1024 + j])));
          float n = tanhf(gin + decBih[2048 + j] + r * (ghn + decBhh[2048 + j]));
          float hold = ws[O_H2 + (long long)j * 32 + b]; // own bytes
          float h2 = (1.f - z) * n + z * hold;
          ws[O_H2 + (long long)j * 32 + b] = h2;
          h2l[j] = h2;
        }
        __syncthreads();
        { // scores
          int wv = tid >> 6, lane = tid & 63;
          float h2v[16];
          #pragma unroll
          for (int i = 0; i < 16; ++i) h2v[i] = h2l[lane + (i << 6)];
          for (int t8 = 0; t8 < 8; ++t8) {
            int tt = wv * 8 + t8;
            const float* eo = ws + O_ENCOUT + ((long long)b * 128 + tt) * 1024 + lane;
            float a = 0;
            #pragma unroll
            for (int i = 0; i < 16; ++i) a += eo[i << 6] * h2v[i];
            #pragma unroll
            for (int off = 32; off; off >>= 1) a += __shfl_xor(a, off, 64);
            if (lane == 0) scl[tt] = a;
          }
        }
        __syncthreads();
        { // softmax over 128
          float v = 0, m = -3.4e38f;
          if (tid < 128) {
            v = scl[tid]; m = v;
            #pragma unroll
            for (int off = 32; off; off >>= 1) m = fmaxf(m, __shfl_xor(m, off, 64));
            if ((tid & 63) == 0) red[tid >> 6] = m;
          }
          __syncthreads();
          float mm = fmaxf(red[0], red[1]);
          float e = 0.f;
          if (tid < 128) {
            e = expf(v - mm);
            float se = e;
            #pragma unroll
            for (int off = 32; off; off >>= 1) se += __shfl_xor(se, off, 64);
            if ((tid & 63) == 0) red[2 + (tid >> 6)] = se;
          }
          __syncthreads();
          if (tid < 128) {
            float wgt = e / (red[2] + red[3]);
            wl[tid] = wgt;
            __builtin_nontemporal_store(wgt, &out[OUT_ATTN + ((long long)s * 32 + b) * 128 + tid]);
          }
        }
        __syncthreads();
        { // context
          int j = tid;
          float a = 0;
          const float* eo = ws + O_ENCOUT + (long long)b * 128 * 1024 + j;
          for (int tt = 0; tt < 128; ++tt) a += wl[tt] * eo[(long long)tt * 1024];
          ws[O_CTXT + (long long)j * 32 + b] = a;
        }
        siga(cnt + SUB_DB + (bid & 7) * 32, tid);
      }

      // ---- DC: av direct (32 blocks), exact chunk order ----
      if (bid < 32) {
        waitgo(go + GO_DC + bid * 32, s + 1, tid);
        int jf = tid >> 5, b = tid & 31;
        int j = (bid << 5) + jf;
        float sum = 0.f;
        #pragma unroll 1
        for (int kp = 0; kp < 16; ++kp) {
          int kk0 = kp * 128;
          const float* src = (kk0 < 1024) ? (ws + O_CTXT + (long long)kk0 * 32)
                                          : (ws + O_H2 + (long long)(kk0 - 1024) * 32);
          #pragma unroll
          for (int r = 0; r < 4; ++r)
            smem[r * 1024 + tid] = cohL(src + r * 1024 + tid);
          __syncthreads();
          const float* wk = ws + O_ATTNWT + (long long)kk0 * 1024 + j;
          float pp = 0.f;
          for (int k = 0; k < 128; ++k)
            pp += smem[k * 32 + b] * wk[(long long)k * 1024];
          sum += pp;
          __syncthreads();
        }
        ws[O_AVT + (long long)j * 32 + b] = tanhf(sum + attnB[j]);
        siga(cnt + SUB_FIN + (bid & 7) * 32, tid);
      }

      // ---- DD: classifier + argmax partials (250 blocks) ----
      if (bid < 250) {
        waitgo(go + GO_DD + bid * 32, s + 1, tid);
        float* wc  = smem;        // [64][128] staged cls weights
        float* sav = smem + 8192; // [64][32] staged av chunk
        int jl = tid & 127, bg = tid >> 7;
        int b0 = bg * 4;
        int j = bid * 128 + jl;
        float acc[4] = {0,0,0,0};
        for (int kc = 0; kc < 1024; kc += 64) {
          #pragma unroll
          for (int i = 0; i < 2; ++i) {
            int t4 = tid + i * 1024;
            int kk = t4 >> 5, c4 = t4 & 31;
            *(f4v*)(wc + kk * 128 + c4 * 4) =
              *(const f4v*)(ws + O_CLSWT + (long long)(kc + kk) * 32000 + bid * 128 + c4 * 4);
          }
          #pragma unroll
          for (int i = 0; i < 2; ++i)
            sav[i * 1024 + tid] = cohL(ws + O_AVT + (long long)kc * 32 + i * 1024 + tid);
          __syncthreads();
          for (int k = 0; k < 64; ++k) {
            float w = wc[k * 128 + jl];
            float4 a = *(const float4*)(sav + k * 32 + b0);
            acc[0] += a.x * w; acc[1] += a.y * w; acc[2] += a.z * w; acc[3] += a.w * w;
          }
          __syncthreads();
        }
        float cb = clsB[j];
        float pvv[4];
        #pragma unroll
        for (int i = 0; i < 4; ++i) {
          pvv[i] = acc[i] + cb;
          __builtin_nontemporal_store(pvv[i], &out[((long long)s * 32 + b0 + i) * 32000 + j]);
        }
        float* lv = smem;
        int*   li = (int*)(smem + 4096);
        __syncthreads();
        #pragma unroll
        for (int i = 0; i < 4; ++i) {
          lv[(b0 + i) * 128 + jl] = pvv[i];
          li[(b0 + i) * 128 + jl] = j;
        }
        __syncthreads();
        float* l2v = smem + 8192;
        int*   l2i = (int*)(smem + 9216);
        {
          int b = tid >> 5, r = tid & 31;
          float bv = -3.4e38f; int bi2 = 0;
          #pragma unroll
          for (int i = 0; i < 4; ++i) {
            float v = lv[b * 128 + r + (i << 5)];
            int ix = li[b * 128 + r + (i << 5)];
            if (v > bv || (v == bv && ix < bi2)) { bv = v; bi2 = ix; }
          }
          l2v[b * 32 + r] = bv; l2i[b * 32 + r] = bi2;
        }
        __syncthreads();
        if (tid < 32) {
          float bv = -3.4e38f; int bi2 = 0;
          for (int r = 0; r < 32; ++r) {
            float v = l2v[tid * 32 + r]; int ix = l2i[tid * 32 + r];
            if (v > bv || (v == bv && ix < bi2)) { bv = v; bi2 = ix; }
          }
          ws[O_PARGV + bid * 32 + tid] = bv;
          ((int*)(ws + O_PARGI))[bid * 32 + tid] = bi2;
        }
        siga(cnt + SUB_DD + (bid & 15) * 32, tid);
      }
    }
  }
}

extern "C" void kernel_launch(void* const* d_in, const int* in_sizes, int n_in,
                              void* d_out, int out_size, void* d_ws, size_t ws_size,
                              hipStream_t stream) {
  const int*   inp    = (const int*)  d_in[0];
  const float* encEmb = (const float*)d_in[1];
  const float* encWih = (const float*)d_in[2];
  const float* encWhh = (const float*)d_in[3];
  const float* encBih = (const float*)d_in[4];
  const float* encBhh = (const float*)d_in[5];
  const float* decEmb = (const float*)d_in[6];
  const float* decWih = (const float*)d_in[7];
  const float* decWhh = (const float*)d_in[8];
  const float* decBih = (const float*)d_in[9];
  const float* decBhh = (const float*)d_in[10];
  const float* attnW  = (const float*)d_in[11];
  const float* attnB  = (const float*)d_in[12];
  const float* clsW   = (const float*)d_in[13];
  const float* clsB   = (const float*)d_in[14];
  float* out = (float*)d_out;
  float* ws  = (float*)d_ws;

  if (ws_size < (size_t)WS_FLOATS * sizeof(float)) return;

  // zero arrival counters + go lines each launch (graph memset node, ordered before kernel)
  (void)hipMemsetAsync(ws + O_CNT, 0, (2048 + 5 * 8192) * sizeof(int), stream);

  void* args[] = { &inp, &encEmb, &encWih, &encWhh, &encBih, &encBhh,
                   &decEmb, &decWih, &decWhh, &decBih, &decBhh,
                   &attnW, &attnB, &clsW, &clsB, &out, &ws };
  (void)hipLaunchCooperativeKernel((void*)seq2seq_kernel, dim3(NBLK), dim3(NTHR),
                                   args, 0, stream);
}

// Round 12
// 45433.231 us; speedup vs baseline: 2.5605x; 2.4989x over previous
//
#include <hip/hip_runtime.h>
#include <hip/hip_cooperative_groups.h>
#include <math.h>

namespace cg = cooperative_groups;

#define NBLK 256
#define NTHR 1024
#define AG  __HIP_MEMORY_SCOPE_AGENT
#define SYS __HIP_MEMORY_SCOPE_SYSTEM

typedef float f4v __attribute__((ext_vector_type(4)));

// Problem sizes
constexpr int Bc = 32, Tc = 128, Ec = 512, Hc = 1024, Ac = 1024, Vc = 32000, Sc = 100;
constexpr long long OUT_ATTN = (long long)Sc * Bc * Vc;

// ---- workspace layout (floats) ----
constexpr long long O_ENCWIH = 0;
constexpr long long O_ENCWHH = O_ENCWIH + (long long)512 * 3072;
constexpr long long O_DECWIH = O_ENCWHH + (long long)1024 * 3072;
constexpr long long O_DECWHH = O_DECWIH + (long long)1536 * 3072;
constexpr long long O_ATTNWT = O_DECWHH + (long long)1024 * 3072;
constexpr long long O_CLSWT  = O_ATTNWT + (long long)2048 * 1024;
constexpr long long O_XENCT  = O_CLSWT + (long long)1024 * 32000;
constexpr long long O_GI     = O_XENCT + (long long)128 * 512 * 32;
constexpr long long O_ENCOUT = O_GI + (long long)128 * 32 * 3072;
constexpr long long O_H0     = O_ENCOUT + (long long)32 * 128 * 1024;  // enc h ping
constexpr long long O_H1     = O_H0 + 32768;                           // enc h pong
constexpr long long O_H2     = O_H1 + 32768;                           // decoder h
constexpr long long O_AVT    = O_H2 + 32768;                           // av^T
constexpr long long O_CTXT   = O_AVT + 32768;                          // context^T
constexpr long long O_PADEC  = O_CTXT + 32768;                         // [10][32][4096]
constexpr long long O_PAENC  = O_PADEC + (long long)10 * 32 * 4096;    // [8][32][3072]
constexpr long long O_PAC    = O_PAENC + (long long)8 * 32 * 3072;     // [16][32][1024]
constexpr long long O_PARGV  = O_PAC + (long long)16 * 32 * 1024;      // [250][32]
constexpr long long O_PARGI  = O_PARGV + 8000;                         // [250][32] int
constexpr long long O_CNT    = O_PARGI + 8000;                         // int[2560] counters
constexpr long long WS_FLOATS = O_CNT + 2560;

// counter lines (int offsets; one 128B line each, 32-int spacing)
#define CI_H    128
#define CI_ENC  160   // + jc*32, jc<8   (160..383)
#define CI_DC   480   // + jc*32, jc<16  (480..959)
#define SUB_DA  1024  // + (bid&15)*32   16 lines, 15 arrivals each
#define SUB_DB  1536  // + (bid&7)*32     8 lines,  4 arrivals each
#define SUB_FIN 1792  // + (jc&7)*32      8 lines,  2 arrivals each
#define SUB_DD  2048  // + (bid&15)*32   16 lines, 16/15 arrivals each

// sc0sc1 (cache-bypassing, coherence-point) loads for mutable cross-block data.
__device__ __forceinline__ float cohL(const float* p) { return __hip_atomic_load(p, __ATOMIC_RELAXED, SYS); }
__device__ __forceinline__ int   cohLi(const int* p) { return __hip_atomic_load(p, __ATOMIC_RELAXED, SYS); }

// Single-line consumer spin (encoder; r9-proven).
__device__ __forceinline__ void spinw(int* c, int tgt, int tid) {
  if (tid == 0) {
    while (__hip_atomic_load(c, __ATOMIC_RELAXED, AG) < tgt)
      __builtin_amdgcn_s_sleep(4);
  }
  __syncthreads();
}
// Producer arrival (r9-proven): stores ack'd -> tid0 release fence (wbl2, no inv) -> RMW.
__device__ __forceinline__ void sigp(int* line, int tid) {
  __syncthreads();
  if (tid == 0) {
    __builtin_amdgcn_fence(__ATOMIC_RELEASE, "agent");
    atomicAdd(line, 1);
  }
}
// Spread-line consumer: threads 0..n-1 each poll a distinct 128B line.
__device__ __forceinline__ void pollsub(const int* base, int n, int tgt, int tid) {
  if (tid < n) {
    while (__hip_atomic_load(base + tid * 32, __ATOMIC_RELAXED, AG) < tgt)
      __builtin_amdgcn_s_sleep(2);
  }
  __syncthreads();
}

__global__ __launch_bounds__(NTHR, 4) void seq2seq_kernel(
    const int* __restrict__ inp, const float* __restrict__ encEmb,
    const float* __restrict__ encWih, const float* __restrict__ encWhh,
    const float* __restrict__ encBih, const float* __restrict__ encBhh,
    const float* __restrict__ decEmb, const float* __restrict__ decWih,
    const float* __restrict__ decWhh, const float* __restrict__ decBih,
    const float* __restrict__ decBhh, const float* __restrict__ attnW,
    const float* __restrict__ attnB, const float* __restrict__ clsW,
    const float* __restrict__ clsB, float* __restrict__ out,
    float* __restrict__ ws)
{
  cg::grid_group grid = cg::this_grid();
  const int bid = blockIdx.x, tid = threadIdx.x;
  const long long gtid = (long long)bid * NTHR + tid;
  int* cnt = (int*)(ws + O_CNT);

  __shared__ float smem[10624];
  int* sflag = (int*)(smem + 10600);
  int* nids  = (int*)(smem + 10368);

  // ======================= P0: transposes + gathers + zeros =======================
  {
    const int sg = tid >> 8, st = tid & 255;
    float* tile = smem + sg * 1056;
    const int c = st & 31, rr = st >> 5;
    for (int it = 0; it < 46; ++it) {
      int job = it * (NBLK * 4) + bid * 4 + sg;
      const float* src = nullptr; float* dst = nullptr;
      int R = 0, C = 0, tr = 0, tcd = 0;
      bool valid = true;
      int j = job;
      if (j < 1536)               { src = encWih; dst = ws + O_ENCWIH; R = 3072;  C = 512;  tr = j >> 4; tcd = j & 15; }
      else if ((j -= 1536) < 3072){ src = encWhh; dst = ws + O_ENCWHH; R = 3072;  C = 1024; tr = j >> 5; tcd = j & 31; }
      else if ((j -= 3072) < 4608){ src = decWih; dst = ws + O_DECWIH; R = 3072;  C = 1536; tr = j / 48; tcd = j % 48; }
      else if ((j -= 4608) < 3072){ src = decWhh; dst = ws + O_DECWHH; R = 3072;  C = 1024; tr = j >> 5; tcd = j & 31; }
      else if ((j -= 3072) < 2048){ src = attnW;  dst = ws + O_ATTNWT; R = 1024;  C = 2048; tr = j >> 6; tcd = j & 63; }
      else if ((j -= 2048) < 32000){src = clsW;   dst = ws + O_CLSWT;  R = 32000; C = 1024; tr = j >> 5; tcd = j & 31; }
      else valid = false;
      if (valid) {
        #pragma unroll
        for (int i = 0; i < 4; ++i) {
          int r = rr + (i << 3);
          tile[r * 33 + c] = src[(long long)(tr * 32 + r) * C + tcd * 32 + c];
        }
      }
      __syncthreads();
      if (valid) {
        #pragma unroll
        for (int i = 0; i < 4; ++i) {
          int c2 = rr + (i << 3);
          dst[(long long)(tcd * 32 + c2) * R + tr * 32 + c] = tile[c * 33 + c2];
        }
      }
      __syncthreads();
    }
  }
  for (long long i = gtid; i < (long long)128 * 512 * 32; i += (long long)NBLK * NTHR) {
    int b = (int)(i & 31);
    int k = (int)((i >> 5) & 511);
    int t = (int)(i >> 14);
    int row = inp[b * Tc + t];
    ws[O_XENCT + i] = encEmb[(long long)row * Ec + k];
  }
  for (long long i = gtid; i < 32768; i += (long long)NBLK * NTHR) {
    ws[O_H0 + i] = 0.f;
    ws[O_AVT + i] = 0.f;
  }
  grid.sync();

  // ======================= P1: Gi =======================
  for (int it = 0; it < 6; ++it) {
    int job = it * NBLK + bid;
    int t = job / 12, jc = job % 12;
    int jl = tid & 255, bq = tid >> 8;
    int j = jc * 256 + jl;
    float acc[8] = {0,0,0,0,0,0,0,0};
    const float* xb = ws + O_XENCT + (long long)t * 512 * 32 + bq * 8;
    const float* wb = ws + O_ENCWIH + j;
    for (int k = 0; k < 512; ++k) {
      float w = wb[(long long)k * 3072];
      float4 x0 = *(const float4*)(xb + k * 32);
      float4 x1 = *(const float4*)(xb + k * 32 + 4);
      acc[0] += x0.x * w; acc[1] += x0.y * w; acc[2] += x0.z * w; acc[3] += x0.w * w;
      acc[4] += x1.x * w; acc[5] += x1.y * w; acc[6] += x1.z * w; acc[7] += x1.w * w;
    }
    float bias = encBih[j];
    #pragma unroll
    for (int i = 0; i < 8; ++i) {
      int b = bq * 8 + i;
      __builtin_nontemporal_store(acc[i] + bias, &ws[O_GI + ((long long)t * 32 + b) * 3072 + j]);
    }
  }
  grid.sync();

  // ======================= P2: encoder GRU (verbatim r9) =======================
  if (bid < 192) {
    int g = bid / 64, rem = bid % 64;
    int jc = rem >> 3, kp = rem & 7;
    for (int t = 0; t < Tc; ++t) {
      long long RD = (t & 1) ? O_H1 : O_H0;
      long long WR = (t & 1) ? O_H0 : O_H1;
      spinw(cnt + CI_H, 8 * t, tid);
      {
        const float* hsrc = ws + RD + kp * 4096;
        #pragma unroll
        for (int r = 0; r < 4; ++r)
          smem[r * 1024 + tid] = cohL(hsrc + r * 1024 + tid);
      }
      __syncthreads();
      int jl = tid & 127, bq = tid >> 7;
      int col = g * 1024 + jc * 128 + jl;
      int b0 = bq * 4;
      float acc[4] = {0,0,0,0};
      const float* hb = smem + b0;
      const float* wb = ws + O_ENCWHH + (long long)(kp * 128) * 3072 + col;
      for (int k = 0; k < 128; ++k) {
        float w = wb[(long long)k * 3072];
        float4 x = *(const float4*)(hb + k * 32);
        acc[0] += x.x * w; acc[1] += x.y * w; acc[2] += x.z * w; acc[3] += x.w * w;
      }
      #pragma unroll
      for (int i = 0; i < 4; ++i)
        ws[O_PAENC + ((long long)(kp * 32) + b0 + i) * 3072 + col] = acc[i];
      __syncthreads();
      if (tid == 0) {
        __builtin_amdgcn_fence(__ATOMIC_RELEASE, "agent");
        int old = atomicAdd(cnt + CI_ENC + jc * 32, 1);
        *sflag = (old == 24 * (t + 1) - 1) ? 1 : 0;
      }
      __syncthreads();
      if (*sflag) {
        int fj = tid & 127, fq = tid >> 7;
        int j = jc * 128 + fj;
        #pragma unroll
        for (int i = 0; i < 4; ++i) {
          int b = fq * 4 + i;
          float gr = 0, gz = 0, gn = 0;
          #pragma unroll
          for (int kp2 = 0; kp2 < 8; ++kp2) {
            long long base = O_PAENC + ((long long)(kp2 * 32) + b) * 3072;
            gr += cohL(&ws[base + j]);
            gz += cohL(&ws[base + 1024 + j]);
            gn += cohL(&ws[base + 2048 + j]);
          }
          long long gib = O_GI + ((long long)t * 32 + b) * 3072;
          float gir = ws[gib + j], giz = ws[gib + 1024 + j], gin = ws[gib + 2048 + j];
          float r = 1.f / (1.f + expf(-(gir + gr + encBhh[j])));
          float z = 1.f / (1.f + expf(-(giz + gz + encBhh[1024 + j])));
          float n = tanhf(gin + r * (gn + encBhh[2048 + j]));
          float hold = cohL(&ws[RD + (long long)j * 32 + b]);
          float hn = (1.f - z) * n + z * hold;
          ws[WR + (long long)j * 32 + b] = hn;
          ws[O_ENCOUT + ((long long)b * 128 + t) * 1024 + j] = hn;
          if (t == Tc - 1) ws[O_H2 + (long long)j * 32 + b] = hn;
        }
        sigp(cnt + CI_H, tid);
      }
      __syncthreads();
    }
  }

  // ======================= P3: decoder, spread-line dataflow =======================
  for (int s = 0; s < Sc; ++s) {
    // ---- DA (240 blocks) ----
    if (bid < 240) {
      int gate, loc;
      if (bid < 80)       { gate = 0; loc = bid; }
      else if (bid < 160) { gate = 1; loc = bid - 80; }
      else if (bid < 208) { gate = 2; loc = bid - 160; }
      else                { gate = 3; loc = bid - 208; }
      int nkp = (gate < 2) ? 10 : ((gate == 2) ? 6 : 4);
      int jc = loc / nkp, kp = loc % nkp;
      int kg = (gate == 3 ? 1536 : 0) + kp * 256;
      bool embp = (kg < 512);
      if (s == 0) {
        spinw(cnt + CI_H, 8 * Tc, tid); // encoder fully done
        if (tid < 32) nids[tid] = 0;
        __syncthreads();
      } else if (embp) {
        // wait DD(s-1): 16 spread lines, line i has (i<10?16:15) arrivals/step
        if (tid < 16) {
          int tgt = ((tid < 10) ? 16 : 15) * s;
          while (__hip_atomic_load(cnt + SUB_DD + tid * 32, __ATOMIC_RELAXED, AG) < tgt)
            __builtin_amdgcn_s_sleep(2);
        }
        __syncthreads();
        // argmax over 250 partials via coh reads (semilattice: order-free)
        float* pv = smem; int* pi = (int*)(smem + 1024);
        int b = tid & 31, ch = tid >> 5;
        float bv = -3.4e38f; int bi = 0;
        for (int r = ch; r < 250; r += 32) {
          float v = cohL(&ws[O_PARGV + r * 32 + b]);
          int ix = cohLi(((int*)(ws + O_PARGI)) + r * 32 + b);
          if (v > bv || (v == bv && ix < bi)) { bv = v; bi = ix; }
        }
        pv[ch * 32 + b] = bv; pi[ch * 32 + b] = bi;
        __syncthreads();
        if (tid < 32) {
          float bb = -3.4e38f; int bbi = 0;
          for (int c2 = 0; c2 < 32; ++c2) {
            float v = pv[c2 * 32 + tid]; int ix = pi[c2 * 32 + tid];
            if (v > bb || (v == bb && ix < bbi)) { bb = v; bbi = ix; }
          }
          nids[tid] = bbi;
        }
        __syncthreads();
      } else if (kg >= 1536) {
        pollsub(cnt + SUB_DB, 8, 4 * s, tid);   // h2(s-1) ready
      } else {
        pollsub(cnt + SUB_FIN, 8, 2 * s, tid);  // av(s-1) ready
      }
      // DA body (verbatim r9)
      int jl = tid & 127, bq = tid >> 7;
      int b0 = bq * 4;
      int jcol = jc * 128 + jl;
      int wcol = (gate >= 2 ? 2048 : gate * 1024) + jcol;
      const float* wb = (kg < 1536) ? (ws + O_DECWIH + (long long)kg * 3072 + wcol)
                                    : (ws + O_DECWHH + (long long)(kg - 1536) * 3072 + wcol);
      float acc[4] = {0,0,0,0};
      if (embp) {
        const float* e0 = decEmb + (long long)nids[b0    ] * 512 + kg;
        const float* e1 = decEmb + (long long)nids[b0 + 1] * 512 + kg;
        const float* e2 = decEmb + (long long)nids[b0 + 2] * 512 + kg;
        const float* e3 = decEmb + (long long)nids[b0 + 3] * 512 + kg;
        for (int k = 0; k < 256; ++k) {
          float w = wb[(long long)k * 3072];
          acc[0] += e0[k] * w; acc[1] += e1[k] * w; acc[2] += e2[k] * w; acc[3] += e3[k] * w;
        }
      } else {
        const float* src = (kg < 1536) ? (ws + O_AVT + (long long)(kg - 512) * 32)
                                       : (ws + O_H2 + (long long)(kg - 1536) * 32);
        #pragma unroll
        for (int r = 0; r < 8; ++r)
          smem[r * 1024 + tid] = cohL(src + r * 1024 + tid);
        __syncthreads();
        const float* xb = smem + b0;
        for (int k = 0; k < 256; ++k) {
          float w = wb[(long long)k * 3072];
          float4 x = *(const float4*)(xb + k * 32);
          acc[0] += x.x * w; acc[1] += x.y * w; acc[2] += x.z * w; acc[3] += x.w * w;
        }
      }
      int colout = gate * 1024 + jcol;
      #pragma unroll
      for (int i = 0; i < 4; ++i)
        ws[O_PADEC + ((long long)(kp * 32) + b0 + i) * 4096 + colout] = acc[i];
      sigp(cnt + SUB_DA + (bid & 15) * 32, tid);
    }

    // ---- DB: gates finalize + attention + context (32 blocks) ----
    if (bid < 32) {
      pollsub(cnt + SUB_DA, 16, 15 * (s + 1), tid);
      int b = bid;
      float* h2l = smem;
      float* scl = smem + 1024;
      float* wl  = smem + 1152;
      float* red = smem + 1280;
      {
        int j = tid;
        float gr = 0, gz = 0, gin = 0, ghn = 0;
        #pragma unroll
        for (int kp = 0; kp < 10; ++kp) {
          long long base = O_PADEC + ((long long)(kp * 32) + b) * 4096;
          gr += cohL(&ws[base + j]);
          gz += cohL(&ws[base + 1024 + j]);
          if (kp < 6) gin += cohL(&ws[base + 2048 + j]);
          if (kp < 4) ghn += cohL(&ws[base + 3072 + j]);
        }
        float r = 1.f / (1.f + expf(-(gr + decBih[j] + decBhh[j])));
        float z = 1.f / (1.f + expf(-(gz + decBih[1024 + j] + decBhh[1024 + j])));
        float n = tanhf(gin + decBih[2048 + j] + r * (ghn + decBhh[2048 + j]));
        float hold = ws[O_H2 + (long long)j * 32 + b]; // own bytes
        float h2 = (1.f - z) * n + z * hold;
        ws[O_H2 + (long long)j * 32 + b] = h2;
        h2l[j] = h2;
      }
      __syncthreads();
      { // scores
        int wv = tid >> 6, lane = tid & 63;
        float h2v[16];
        #pragma unroll
        for (int i = 0; i < 16; ++i) h2v[i] = h2l[lane + (i << 6)];
        for (int t8 = 0; t8 < 8; ++t8) {
          int tt = wv * 8 + t8;
          const float* eo = ws + O_ENCOUT + ((long long)b * 128 + tt) * 1024 + lane;
          float a = 0;
          #pragma unroll
          for (int i = 0; i < 16; ++i) a += eo[i << 6] * h2v[i];
          #pragma unroll
          for (int off = 32; off; off >>= 1) a += __shfl_xor(a, off, 64);
          if (lane == 0) scl[tt] = a;
        }
      }
      __syncthreads();
      { // softmax over 128
        float v = 0, m = -3.4e38f;
        if (tid < 128) {
          v = scl[tid]; m = v;
          #pragma unroll
          for (int off = 32; off; off >>= 1) m = fmaxf(m, __shfl_xor(m, off, 64));
          if ((tid & 63) == 0) red[tid >> 6] = m;
        }
        __syncthreads();
        float mm = fmaxf(red[0], red[1]);
        float e = 0.f;
        if (tid < 128) {
          e = expf(v - mm);
          float se = e;
          #pragma unroll
          for (int off = 32; off; off >>= 1) se += __shfl_xor(se, off, 64);
          if ((tid & 63) == 0) red[2 + (tid >> 6)] = se;
        }
        __syncthreads();
        if (tid < 128) {
          float wgt = e / (red[2] + red[3]);
          wl[tid] = wgt;
          __builtin_nontemporal_store(wgt, &out[OUT_ATTN + ((long long)s * 32 + b) * 128 + tid]);
        }
      }
      __syncthreads();
      { // context
        int j = tid;
        float a = 0;
        const float* eo = ws + O_ENCOUT + (long long)b * 128 * 1024 + j;
        for (int tt = 0; tt < 128; ++tt) a += wl[tt] * eo[(long long)tt * 1024];
        ws[O_CTXT + (long long)j * 32 + b] = a;
      }
      sigp(cnt + SUB_DB + (bid & 7) * 32, tid);
    }

    // ---- DC: av partials (all 256 blocks) + last-arriver DCfin (verbatim r9) ----
    {
      pollsub(cnt + SUB_DB, 8, 4 * (s + 1), tid);
      int jc = bid >> 4, kp = bid & 15;
      int kk0 = kp * 128;
      {
        const float* src = (kk0 < 1024) ? (ws + O_CTXT + (long long)kk0 * 32)
                                        : (ws + O_H2 + (long long)(kk0 - 1024) * 32);
        #pragma unroll
        for (int r = 0; r < 4; ++r)
          smem[r * 1024 + tid] = cohL(src + r * 1024 + tid);
      }
      __syncthreads();
      int jl = tid & 63, bh = tid >> 6;
      int b0 = bh * 2;
      int j = jc * 64 + jl;
      float acc0 = 0, acc1 = 0;
      const float* wb = ws + O_ATTNWT + (long long)kk0 * 1024 + j;
      const float* xb = smem + b0;
      for (int k = 0; k < 128; ++k) {
        float w = wb[(long long)k * 1024];
        float2 x = *(const float2*)(xb + k * 32);
        acc0 += x.x * w; acc1 += x.y * w;
      }
      ws[O_PAC + ((long long)(kp * 32) + b0) * 1024 + j] = acc0;
      ws[O_PAC + ((long long)(kp * 32) + b0 + 1) * 1024 + j] = acc1;
      __syncthreads();
      if (tid == 0) {
        __builtin_amdgcn_fence(__ATOMIC_RELEASE, "agent");
        int old = atomicAdd(cnt + CI_DC + jc * 32, 1);
        *sflag = (old == 16 * (s + 1) - 1) ? 1 : 0;
      }
      __syncthreads();
      if (*sflag) { // last arriver: DCfin for this jc (exact kp order)
        #pragma unroll
        for (int o = 0; o < 2; ++o) {
          int oo = tid + o * 1024;
          int j2 = jc * 64 + (oo >> 5), b = oo & 31;
          float sum = 0;
          #pragma unroll
          for (int kp2 = 0; kp2 < 16; ++kp2)
            sum += cohL(&ws[O_PAC + ((long long)(kp2 * 32) + b) * 1024 + j2]);
          ws[O_AVT + (long long)j2 * 32 + b] = tanhf(sum + attnB[j2]);
        }
        sigp(cnt + SUB_FIN + (jc & 7) * 32, tid);
      }
      __syncthreads();
    }

    // ---- DD: classifier + argmax partials (250 blocks; NT clsW stream) ----
    if (bid < 250) {
      pollsub(cnt + SUB_FIN, 8, 2 * (s + 1), tid);
      float* wc  = smem;        // [64][128] staged cls weights
      float* sav = smem + 8192; // [64][32] staged av chunk
      int jl = tid & 127, bg = tid >> 7;
      int b0 = bg * 4;
      int j = bid * 128 + jl;
      float acc[4] = {0,0,0,0};
      for (int kc = 0; kc < 1024; kc += 64) {
        #pragma unroll
        for (int i = 0; i < 2; ++i) {
          int t4 = tid + i * 1024;
          int kk = t4 >> 5, c4 = t4 & 31;
          f4v wv = __builtin_nontemporal_load(
            (const f4v*)(ws + O_CLSWT + (long long)(kc + kk) * 32000 + bid * 128 + c4 * 4));
          *(f4v*)(wc + kk * 128 + c4 * 4) = wv;
        }
        #pragma unroll
        for (int i = 0; i < 2; ++i)
          sav[i * 1024 + tid] = cohL(ws + O_AVT + (long long)kc * 32 + i * 1024 + tid);
        __syncthreads();
        for (int k = 0; k < 64; ++k) {
          float w = wc[k * 128 + jl];
          float4 a = *(const float4*)(sav + k * 32 + b0);
          acc[0] += a.x * w; acc[1] += a.y * w; acc[2] += a.z * w; acc[3] += a.w * w;
        }
        __syncthreads();
      }
      float cb = clsB[j];
      float pvv[4];
      #pragma unroll
      for (int i = 0; i < 4; ++i) {
        pvv[i] = acc[i] + cb;
        __builtin_nontemporal_store(pvv[i], &out[((long long)s * 32 + b0 + i) * 32000 + j]);
      }
      float* lv = smem;
      int*   li = (int*)(smem + 4096);
      __syncthreads();
      #pragma unroll
      for (int i = 0; i < 4; ++i) {
        lv[(b0 + i) * 128 + jl] = pvv[i];
        li[(b0 + i) * 128 + jl] = j;
      }
      __syncthreads();
      float* l2v = smem + 8192;
      int*   l2i = (int*)(smem + 9216);
      {
        int b = tid >> 5, r = tid & 31;
        float bv = -3.4e38f; int bi2 = 0;
        #pragma unroll
        for (int i = 0; i < 4; ++i) {
          float v = lv[b * 128 + r + (i << 5)];
          int ix = li[b * 128 + r + (i << 5)];
          if (v > bv || (v == bv && ix < bi2)) { bv = v; bi2 = ix; }
        }
        l2v[b * 32 + r] = bv; l2i[b * 32 + r] = bi2;
      }
      __syncthreads();
      if (tid < 32) {
        float bv = -3.4e38f; int bi2 = 0;
        for (int r = 0; r < 32; ++r) {
          float v = l2v[tid * 32 + r]; int ix = l2i[tid * 32 + r];
          if (v > bv || (v == bv && ix < bi2)) { bv = v; bi2 = ix; }
        }
        ws[O_PARGV + bid * 32 + tid] = bv;
        ((int*)(ws + O_PARGI))[bid * 32 + tid] = bi2;
      }
      sigp(cnt + SUB_DD + (bid & 15) * 32, tid);
    }
  }
}

extern "C" void kernel_launch(void* const* d_in, const int* in_sizes, int n_in,
                              void* d_out, int out_size, void* d_ws, size_t ws_size,
                              hipStream_t stream) {
  const int*   inp    = (const int*)  d_in[0];
  const float* encEmb = (const float*)d_in[1];
  const float* encWih = (const float*)d_in[2];
  const float* encWhh = (const float*)d_in[3];
  const float* encBih = (const float*)d_in[4];
  const float* encBhh = (const float*)d_in[5];
  const float* decEmb = (const float*)d_in[6];
  const float* decWih = (const float*)d_in[7];
  const float* decWhh = (const float*)d_in[8];
  const float* decBih = (const float*)d_in[9];
  const float* decBhh = (const float*)d_in[10];
  const float* attnW  = (const float*)d_in[11];
  const float* attnB  = (const float*)d_in[12];
  const float* clsW   = (const float*)d_in[13];
  const float* clsB   = (const float*)d_in[14];
  float* out = (float*)d_out;
  float* ws  = (float*)d_ws;

  if (ws_size < (size_t)WS_FLOATS * sizeof(float)) return;

  // zero counters each launch (graph memset node, ordered before kernel)
  (void)hipMemsetAsync(ws + O_CNT, 0, 2560 * sizeof(int), stream);

  void* args[] = { &inp, &encEmb, &encWih, &encWhh, &encBih, &encBhh,
                   &decEmb, &decWih, &decWhh, &decBih, &decBhh,
                   &attnW, &attnB, &clsW, &clsB, &out, &ws };
  (void)hipLaunchCooperativeKernel((void*)seq2seq_kernel, dim3(NBLK), dim3(NTHR),
                                   args, 0, stream);
}

// Round 13
// 39642.169 us; speedup vs baseline: 2.9345x; 1.1461x over previous
//
#include <hip/hip_runtime.h>
#include <hip/hip_cooperative_groups.h>
#include <math.h>

namespace cg = cooperative_groups;

#define NBLK 256
#define NTHR 1024
#define AG  __HIP_MEMORY_SCOPE_AGENT
#define SYS __HIP_MEMORY_SCOPE_SYSTEM

typedef float f4v __attribute__((ext_vector_type(4)));

// Problem sizes
constexpr int Bc = 32, Tc = 128, Ec = 512, Hc = 1024, Ac = 1024, Vc = 32000, Sc = 100;
constexpr long long OUT_ATTN = (long long)Sc * Bc * Vc;

// ---- workspace layout (floats) ----
constexpr long long O_ENCWIH = 0;
constexpr long long O_ENCWHH = O_ENCWIH + (long long)512 * 3072;
constexpr long long O_DECWIH = O_ENCWHH + (long long)1024 * 3072;
constexpr long long O_DECWHH = O_DECWIH + (long long)1536 * 3072;
constexpr long long O_ATTNWT = O_DECWHH + (long long)1024 * 3072;
constexpr long long O_CLSWT  = O_ATTNWT + (long long)2048 * 1024;
constexpr long long O_XENCT  = O_CLSWT + (long long)1024 * 32000;
constexpr long long O_GI     = O_XENCT + (long long)128 * 512 * 32;
constexpr long long O_ENCOUT = O_GI + (long long)128 * 32 * 3072;
constexpr long long O_H0     = O_ENCOUT + (long long)32 * 128 * 1024;  // enc h ping
constexpr long long O_H1     = O_H0 + 32768;                           // enc h pong
constexpr long long O_H2     = O_H1 + 32768;                           // decoder h
constexpr long long O_AVT    = O_H2 + 32768;                           // av^T
constexpr long long O_CTXT   = O_AVT + 32768;                          // context^T
constexpr long long O_PADEC  = O_CTXT + 32768;                         // [10][32][4096]
constexpr long long O_PAENC  = O_PADEC + (long long)10 * 32 * 4096;    // [8][32][3072]
constexpr long long O_PAC    = O_PAENC + (long long)8 * 32 * 3072;     // [16][32][1024]
constexpr long long O_PARGV  = O_PAC + (long long)16 * 32 * 1024;      // [250][32]
constexpr long long O_PARGI  = O_PARGV + 8000;                         // [250][32] int
constexpr long long O_CNT    = O_PARGI + 8000;                         // int[2560] counters
constexpr long long WS_FLOATS = O_CNT + 2560;

// counter lines (int offsets; one 128B line each, 32-int spacing)
#define CI_H    128
#define CI_ENC  160   // + jc*32, jc<8   (160..383)
#define CI_DC   480   // + jc*32, jc<16  (480..959)
#define SUB_DA  1024  // + (bid&15)*32   16 lines, 15 arrivals each
#define SUB_DB  1536  // + (bid&7)*32     8 lines,  4 arrivals each
#define SUB_FIN 1792  // + (jc&7)*32      8 lines,  2 arrivals each
#define SUB_DD  2048  // + (bid&15)*32   16 lines, 16/15 arrivals each

// sc0sc1 (cache-bypassing, coherence-point) loads for mutable cross-block data.
__device__ __forceinline__ float cohL(const float* p) { return __hip_atomic_load(p, __ATOMIC_RELAXED, SYS); }
__device__ __forceinline__ int   cohLi(const int* p) { return __hip_atomic_load(p, __ATOMIC_RELAXED, SYS); }

// Single-line consumer spin (encoder; r9-proven).
__device__ __forceinline__ void spinw(int* c, int tgt, int tid) {
  if (tid == 0) {
    while (__hip_atomic_load(c, __ATOMIC_RELAXED, AG) < tgt)
      __builtin_amdgcn_s_sleep(4);
  }
  __syncthreads();
}
// Producer arrival (r9-proven): stores ack'd -> tid0 release fence (wbl2, no inv) -> RMW.
__device__ __forceinline__ void sigp(int* line, int tid) {
  __syncthreads();
  if (tid == 0) {
    __builtin_amdgcn_fence(__ATOMIC_RELEASE, "agent");
    atomicAdd(line, 1);
  }
}
// Spread-line consumer: threads 0..n-1 each poll a distinct 128B line.
__device__ __forceinline__ void pollsub(const int* base, int n, int tgt, int tid) {
  if (tid < n) {
    while (__hip_atomic_load(base + tid * 32, __ATOMIC_RELAXED, AG) < tgt)
      __builtin_amdgcn_s_sleep(2);
  }
  __syncthreads();
}
// LDS-only barrier: drain ds ops, rendezvous — global loads STAY IN FLIGHT.
__device__ __forceinline__ void ldsbar() {
  asm volatile("s_waitcnt lgkmcnt(0)" ::: "memory");
  __builtin_amdgcn_s_barrier();
}

__global__ __launch_bounds__(NTHR, 4) void seq2seq_kernel(
    const int* __restrict__ inp, const float* __restrict__ encEmb,
    const float* __restrict__ encWih, const float* __restrict__ encWhh,
    const float* __restrict__ encBih, const float* __restrict__ encBhh,
    const float* __restrict__ decEmb, const float* __restrict__ decWih,
    const float* __restrict__ decWhh, const float* __restrict__ decBih,
    const float* __restrict__ decBhh, const float* __restrict__ attnW,
    const float* __restrict__ attnB, const float* __restrict__ clsW,
    const float* __restrict__ clsB, float* __restrict__ out,
    float* __restrict__ ws)
{
  cg::grid_group grid = cg::this_grid();
  const int bid = blockIdx.x, tid = threadIdx.x;
  const long long gtid = (long long)bid * NTHR + tid;
  int* cnt = (int*)(ws + O_CNT);

  __shared__ float smem[10624];
  int* sflag = (int*)(smem + 10600);
  int* nids  = (int*)(smem + 10368);

  // ======================= P0: transposes + gathers + zeros =======================
  {
    const int sg = tid >> 8, st = tid & 255;
    float* tile = smem + sg * 1056;
    const int c = st & 31, rr = st >> 5;
    for (int it = 0; it < 46; ++it) {
      int job = it * (NBLK * 4) + bid * 4 + sg;
      const float* src = nullptr; float* dst = nullptr;
      int R = 0, C = 0, tr = 0, tcd = 0;
      bool valid = true;
      int j = job;
      if (j < 1536)               { src = encWih; dst = ws + O_ENCWIH; R = 3072;  C = 512;  tr = j >> 4; tcd = j & 15; }
      else if ((j -= 1536) < 3072){ src = encWhh; dst = ws + O_ENCWHH; R = 3072;  C = 1024; tr = j >> 5; tcd = j & 31; }
      else if ((j -= 3072) < 4608){ src = decWih; dst = ws + O_DECWIH; R = 3072;  C = 1536; tr = j / 48; tcd = j % 48; }
      else if ((j -= 4608) < 3072){ src = decWhh; dst = ws + O_DECWHH; R = 3072;  C = 1024; tr = j >> 5; tcd = j & 31; }
      else if ((j -= 3072) < 2048){ src = attnW;  dst = ws + O_ATTNWT; R = 1024;  C = 2048; tr = j >> 6; tcd = j & 63; }
      else if ((j -= 2048) < 32000){src = clsW;   dst = ws + O_CLSWT;  R = 32000; C = 1024; tr = j >> 5; tcd = j & 31; }
      else valid = false;
      if (valid) {
        #pragma unroll
        for (int i = 0; i < 4; ++i) {
          int r = rr + (i << 3);
          tile[r * 33 + c] = src[(long long)(tr * 32 + r) * C + tcd * 32 + c];
        }
      }
      __syncthreads();
      if (valid) {
        #pragma unroll
        for (int i = 0; i < 4; ++i) {
          int c2 = rr + (i << 3);
          dst[(long long)(tcd * 32 + c2) * R + tr * 32 + c] = tile[c * 33 + c2];
        }
      }
      __syncthreads();
    }
  }
  for (long long i = gtid; i < (long long)128 * 512 * 32; i += (long long)NBLK * NTHR) {
    int b = (int)(i & 31);
    int k = (int)((i >> 5) & 511);
    int t = (int)(i >> 14);
    int row = inp[b * Tc + t];
    ws[O_XENCT + i] = encEmb[(long long)row * Ec + k];
  }
  for (long long i = gtid; i < 32768; i += (long long)NBLK * NTHR) {
    ws[O_H0 + i] = 0.f;
    ws[O_AVT + i] = 0.f;
  }
  grid.sync();

  // ======================= P1: Gi =======================
  for (int it = 0; it < 6; ++it) {
    int job = it * NBLK + bid;
    int t = job / 12, jc = job % 12;
    int jl = tid & 255, bq = tid >> 8;
    int j = jc * 256 + jl;
    float acc[8] = {0,0,0,0,0,0,0,0};
    const float* xb = ws + O_XENCT + (long long)t * 512 * 32 + bq * 8;
    const float* wb = ws + O_ENCWIH + j;
    for (int k = 0; k < 512; ++k) {
      float w = wb[(long long)k * 3072];
      float4 x0 = *(const float4*)(xb + k * 32);
      float4 x1 = *(const float4*)(xb + k * 32 + 4);
      acc[0] += x0.x * w; acc[1] += x0.y * w; acc[2] += x0.z * w; acc[3] += x0.w * w;
      acc[4] += x1.x * w; acc[5] += x1.y * w; acc[6] += x1.z * w; acc[7] += x1.w * w;
    }
    float bias = encBih[j];
    #pragma unroll
    for (int i = 0; i < 8; ++i) {
      int b = bq * 8 + i;
      __builtin_nontemporal_store(acc[i] + bias, &ws[O_GI + ((long long)t * 32 + b) * 3072 + j]);
    }
  }
  grid.sync();

  // ======================= P2: encoder GRU (verbatim r9/r12) =======================
  if (bid < 192) {
    int g = bid / 64, rem = bid % 64;
    int jc = rem >> 3, kp = rem & 7;
    for (int t = 0; t < Tc; ++t) {
      long long RD = (t & 1) ? O_H1 : O_H0;
      long long WR = (t & 1) ? O_H0 : O_H1;
      spinw(cnt + CI_H, 8 * t, tid);
      {
        const float* hsrc = ws + RD + kp * 4096;
        #pragma unroll
        for (int r = 0; r < 4; ++r)
          smem[r * 1024 + tid] = cohL(hsrc + r * 1024 + tid);
      }
      __syncthreads();
      int jl = tid & 127, bq = tid >> 7;
      int col = g * 1024 + jc * 128 + jl;
      int b0 = bq * 4;
      float acc[4] = {0,0,0,0};
      const float* hb = smem + b0;
      const float* wb = ws + O_ENCWHH + (long long)(kp * 128) * 3072 + col;
      for (int k = 0; k < 128; ++k) {
        float w = wb[(long long)k * 3072];
        float4 x = *(const float4*)(hb + k * 32);
        acc[0] += x.x * w; acc[1] += x.y * w; acc[2] += x.z * w; acc[3] += x.w * w;
      }
      #pragma unroll
      for (int i = 0; i < 4; ++i)
        ws[O_PAENC + ((long long)(kp * 32) + b0 + i) * 3072 + col] = acc[i];
      __syncthreads();
      if (tid == 0) {
        __builtin_amdgcn_fence(__ATOMIC_RELEASE, "agent");
        int old = atomicAdd(cnt + CI_ENC + jc * 32, 1);
        *sflag = (old == 24 * (t + 1) - 1) ? 1 : 0;
      }
      __syncthreads();
      if (*sflag) {
        int fj = tid & 127, fq = tid >> 7;
        int j = jc * 128 + fj;
        #pragma unroll
        for (int i = 0; i < 4; ++i) {
          int b = fq * 4 + i;
          float gr = 0, gz = 0, gn = 0;
          #pragma unroll
          for (int kp2 = 0; kp2 < 8; ++kp2) {
            long long base = O_PAENC + ((long long)(kp2 * 32) + b) * 3072;
            gr += cohL(&ws[base + j]);
            gz += cohL(&ws[base + 1024 + j]);
            gn += cohL(&ws[base + 2048 + j]);
          }
          long long gib = O_GI + ((long long)t * 32 + b) * 3072;
          float gir = ws[gib + j], giz = ws[gib + 1024 + j], gin = ws[gib + 2048 + j];
          float r = 1.f / (1.f + expf(-(gir + gr + encBhh[j])));
          float z = 1.f / (1.f + expf(-(giz + gz + encBhh[1024 + j])));
          float n = tanhf(gin + r * (gn + encBhh[2048 + j]));
          float hold = cohL(&ws[RD + (long long)j * 32 + b]);
          float hn = (1.f - z) * n + z * hold;
          ws[WR + (long long)j * 32 + b] = hn;
          ws[O_ENCOUT + ((long long)b * 128 + t) * 1024 + j] = hn;
          if (t == Tc - 1) ws[O_H2 + (long long)j * 32 + b] = hn;
        }
        sigp(cnt + CI_H, tid);
      }
      __syncthreads();
    }
  }

  // ======================= P3: decoder, spread-line dataflow =======================
  for (int s = 0; s < Sc; ++s) {
    // ---- DA (240 blocks) ----
    if (bid < 240) {
      int gate, loc;
      if (bid < 80)       { gate = 0; loc = bid; }
      else if (bid < 160) { gate = 1; loc = bid - 80; }
      else if (bid < 208) { gate = 2; loc = bid - 160; }
      else                { gate = 3; loc = bid - 208; }
      int nkp = (gate < 2) ? 10 : ((gate == 2) ? 6 : 4);
      int jc = loc / nkp, kp = loc % nkp;
      int kg = (gate == 3 ? 1536 : 0) + kp * 256;
      bool embp = (kg < 512);
      if (s == 0) {
        spinw(cnt + CI_H, 8 * Tc, tid); // encoder fully done
        if (tid < 32) nids[tid] = 0;
        __syncthreads();
      } else if (embp) {
        // wait DD(s-1): 16 spread lines, line i has (i<10?16:15) arrivals/step
        if (tid < 16) {
          int tgt = ((tid < 10) ? 16 : 15) * s;
          while (__hip_atomic_load(cnt + SUB_DD + tid * 32, __ATOMIC_RELAXED, AG) < tgt)
            __builtin_amdgcn_s_sleep(2);
        }
        __syncthreads();
        // argmax over 250 partials via coh reads (semilattice: order-free)
        float* pv = smem; int* pi = (int*)(smem + 1024);
        int b = tid & 31, ch = tid >> 5;
        float bv = -3.4e38f; int bi = 0;
        for (int r = ch; r < 250; r += 32) {
          float v = cohL(&ws[O_PARGV + r * 32 + b]);
          int ix = cohLi(((int*)(ws + O_PARGI)) + r * 32 + b);
          if (v > bv || (v == bv && ix < bi)) { bv = v; bi = ix; }
        }
        pv[ch * 32 + b] = bv; pi[ch * 32 + b] = bi;
        __syncthreads();
        if (tid < 32) {
          float bb = -3.4e38f; int bbi = 0;
          for (int c2 = 0; c2 < 32; ++c2) {
            float v = pv[c2 * 32 + tid]; int ix = pi[c2 * 32 + tid];
            if (v > bb || (v == bb && ix < bbi)) { bb = v; bbi = ix; }
          }
          nids[tid] = bbi;
        }
        __syncthreads();
      } else if (kg >= 1536) {
        pollsub(cnt + SUB_DB, 8, 4 * s, tid);   // h2(s-1) ready
      } else {
        pollsub(cnt + SUB_FIN, 8, 2 * s, tid);  // av(s-1) ready
      }
      // DA body (verbatim r9)
      int jl = tid & 127, bq = tid >> 7;
      int b0 = bq * 4;
      int jcol = jc * 128 + jl;
      int wcol = (gate >= 2 ? 2048 : gate * 1024) + jcol;
      const float* wb = (kg < 1536) ? (ws + O_DECWIH + (long long)kg * 3072 + wcol)
                                    : (ws + O_DECWHH + (long long)(kg - 1536) * 3072 + wcol);
      float acc[4] = {0,0,0,0};
      if (embp) {
        const float* e0 = decEmb + (long long)nids[b0    ] * 512 + kg;
        const float* e1 = decEmb + (long long)nids[b0 + 1] * 512 + kg;
        const float* e2 = decEmb + (long long)nids[b0 + 2] * 512 + kg;
        const float* e3 = decEmb + (long long)nids[b0 + 3] * 512 + kg;
        for (int k = 0; k < 256; ++k) {
          float w = wb[(long long)k * 3072];
          acc[0] += e0[k] * w; acc[1] += e1[k] * w; acc[2] += e2[k] * w; acc[3] += e3[k] * w;
        }
      } else {
        const float* src = (kg < 1536) ? (ws + O_AVT + (long long)(kg - 512) * 32)
                                       : (ws + O_H2 + (long long)(kg - 1536) * 32);
        #pragma unroll
        for (int r = 0; r < 8; ++r)
          smem[r * 1024 + tid] = cohL(src + r * 1024 + tid);
        __syncthreads();
        const float* xb = smem + b0;
        for (int k = 0; k < 256; ++k) {
          float w = wb[(long long)k * 3072];
          float4 x = *(const float4*)(xb + k * 32);
          acc[0] += x.x * w; acc[1] += x.y * w; acc[2] += x.z * w; acc[3] += x.w * w;
        }
      }
      int colout = gate * 1024 + jcol;
      #pragma unroll
      for (int i = 0; i < 4; ++i)
        ws[O_PADEC + ((long long)(kp * 32) + b0 + i) * 4096 + colout] = acc[i];
      sigp(cnt + SUB_DA + (bid & 15) * 32, tid);
    }

    // ---- DB: gates finalize + attention + context (32 blocks) ----
    if (bid < 32) {
      pollsub(cnt + SUB_DA, 16, 15 * (s + 1), tid);
      int b = bid;
      float* h2l = smem;
      float* scl = smem + 1024;
      float* wl  = smem + 1152;
      float* red = smem + 1280;
      {
        int j = tid;
        float gr = 0, gz = 0, gin = 0, ghn = 0;
        #pragma unroll
        for (int kp = 0; kp < 10; ++kp) {
          long long base = O_PADEC + ((long long)(kp * 32) + b) * 4096;
          gr += cohL(&ws[base + j]);
          gz += cohL(&ws[base + 1024 + j]);
          if (kp < 6) gin += cohL(&ws[base + 2048 + j]);
          if (kp < 4) ghn += cohL(&ws[base + 3072 + j]);
        }
        float r = 1.f / (1.f + expf(-(gr + decBih[j] + decBhh[j])));
        float z = 1.f / (1.f + expf(-(gz + decBih[1024 + j] + decBhh[1024 + j])));
        float n = tanhf(gin + decBih[2048 + j] + r * (ghn + decBhh[2048 + j]));
        float hold = ws[O_H2 + (long long)j * 32 + b]; // own bytes
        float h2 = (1.f - z) * n + z * hold;
        ws[O_H2 + (long long)j * 32 + b] = h2;
        h2l[j] = h2;
      }
      __syncthreads();
      { // scores
        int wv = tid >> 6, lane = tid & 63;
        float h2v[16];
        #pragma unroll
        for (int i = 0; i < 16; ++i) h2v[i] = h2l[lane + (i << 6)];
        for (int t8 = 0; t8 < 8; ++t8) {
          int tt = wv * 8 + t8;
          const float* eo = ws + O_ENCOUT + ((long long)b * 128 + tt) * 1024 + lane;
          float a = 0;
          #pragma unroll
          for (int i = 0; i < 16; ++i) a += eo[i << 6] * h2v[i];
          #pragma unroll
          for (int off = 32; off; off >>= 1) a += __shfl_xor(a, off, 64);
          if (lane == 0) scl[tt] = a;
        }
      }
      __syncthreads();
      { // softmax over 128
        float v = 0, m = -3.4e38f;
        if (tid < 128) {
          v = scl[tid]; m = v;
          #pragma unroll
          for (int off = 32; off; off >>= 1) m = fmaxf(m, __shfl_xor(m, off, 64));
          if ((tid & 63) == 0) red[tid >> 6] = m;
        }
        __syncthreads();
        float mm = fmaxf(red[0], red[1]);
        float e = 0.f;
        if (tid < 128) {
          e = expf(v - mm);
          float se = e;
          #pragma unroll
          for (int off = 32; off; off >>= 1) se += __shfl_xor(se, off, 64);
          if ((tid & 63) == 0) red[2 + (tid >> 6)] = se;
        }
        __syncthreads();
        if (tid < 128) {
          float wgt = e / (red[2] + red[3]);
          wl[tid] = wgt;
          __builtin_nontemporal_store(wgt, &out[OUT_ATTN + ((long long)s * 32 + b) * 128 + tid]);
        }
      }
      __syncthreads();
      { // context
        int j = tid;
        float a = 0;
        const float* eo = ws + O_ENCOUT + (long long)b * 128 * 1024 + j;
        for (int tt = 0; tt < 128; ++tt) a += wl[tt] * eo[(long long)tt * 1024];
        ws[O_CTXT + (long long)j * 32 + b] = a;
      }
      sigp(cnt + SUB_DB + (bid & 7) * 32, tid);
    }

    // ---- DC: av partials (all 256 blocks) + last-arriver DCfin (verbatim r12) ----
    {
      pollsub(cnt + SUB_DB, 8, 4 * (s + 1), tid);
      int jc = bid >> 4, kp = bid & 15;
      int kk0 = kp * 128;
      {
        const float* src = (kk0 < 1024) ? (ws + O_CTXT + (long long)kk0 * 32)
                                        : (ws + O_H2 + (long long)(kk0 - 1024) * 32);
        #pragma unroll
        for (int r = 0; r < 4; ++r)
          smem[r * 1024 + tid] = cohL(src + r * 1024 + tid);
      }
      __syncthreads();
      int jl = tid & 63, bh = tid >> 6;
      int b0 = bh * 2;
      int j = jc * 64 + jl;
      float acc0 = 0, acc1 = 0;
      const float* wb = ws + O_ATTNWT + (long long)kk0 * 1024 + j;
      const float* xb = smem + b0;
      for (int k = 0; k < 128; ++k) {
        float w = wb[(long long)k * 1024];
        float2 x = *(const float2*)(xb + k * 32);
        acc0 += x.x * w; acc1 += x.y * w;
      }
      ws[O_PAC + ((long long)(kp * 32) + b0) * 1024 + j] = acc0;
      ws[O_PAC + ((long long)(kp * 32) + b0 + 1) * 1024 + j] = acc1;
      __syncthreads();
      if (tid == 0) {
        __builtin_amdgcn_fence(__ATOMIC_RELEASE, "agent");
        int old = atomicAdd(cnt + CI_DC + jc * 32, 1);
        *sflag = (old == 16 * (s + 1) - 1) ? 1 : 0;
      }
      __syncthreads();
      if (*sflag) { // last arriver: DCfin for this jc (exact kp order)
        #pragma unroll
        for (int o = 0; o < 2; ++o) {
          int oo = tid + o * 1024;
          int j2 = jc * 64 + (oo >> 5), b = oo & 31;
          float sum = 0;
          #pragma unroll
          for (int kp2 = 0; kp2 < 16; ++kp2)
            sum += cohL(&ws[O_PAC + ((long long)(kp2 * 32) + b) * 1024 + j2]);
          ws[O_AVT + (long long)j2 * 32 + b] = tanhf(sum + attnB[j2]);
        }
        sigp(cnt + SUB_FIN + (jc & 7) * 32, tid);
      }
      __syncthreads();
    }

    // ---- DD: classifier + argmax partials (250 blocks; 2-deep prefetched NT clsW) ----
    if (bid < 250) {
      pollsub(cnt + SUB_FIN, 8, 2 * (s + 1), tid);
      float* wc  = smem;        // [64][128] staged cls weights
      float* sav = smem + 8192; // [64][32] staged av chunk
      const int jl = tid & 127, bg = tid >> 7;
      const int b0 = bg * 4;
      const int j = bid * 128 + jl;
      const int kk0 = tid >> 5, kk1 = 32 + (tid >> 5);
      const int c4 = (tid & 31) * 4;
      const float* wsrc = ws + O_CLSWT + bid * 128 + c4;
      float acc[4] = {0,0,0,0};
      f4v pa0, pa1, pb0, pb1;
      float sa0, sa1, sb0, sb1;
      // prologue: issue chunks 0 (A) and 1 (B); stay in flight across ldsbar()
      pa0 = __builtin_nontemporal_load((const f4v*)(wsrc + (long long)(kk0) * 32000));
      pa1 = __builtin_nontemporal_load((const f4v*)(wsrc + (long long)(kk1) * 32000));
      sa0 = cohL(ws + O_AVT + tid);
      sa1 = cohL(ws + O_AVT + 1024 + tid);
      pb0 = __builtin_nontemporal_load((const f4v*)(wsrc + (long long)(64 + kk0) * 32000));
      pb1 = __builtin_nontemporal_load((const f4v*)(wsrc + (long long)(64 + kk1) * 32000));
      sb0 = cohL(ws + O_AVT + 2048 + tid);
      sb1 = cohL(ws + O_AVT + 2048 + 1024 + tid);
      #pragma unroll 1
      for (int kc = 0; kc < 16; kc += 2) {
        // --- even chunk (A regs) ---
        *(f4v*)(wc + kk0 * 128 + c4) = pa0;
        *(f4v*)(wc + kk1 * 128 + c4) = pa1;
        sav[tid] = sa0; sav[1024 + tid] = sa1;
        ldsbar();
        if (kc + 2 < 16) {
          pa0 = __builtin_nontemporal_load((const f4v*)(wsrc + (long long)((kc + 2) * 64 + kk0) * 32000));
          pa1 = __builtin_nontemporal_load((const f4v*)(wsrc + (long long)((kc + 2) * 64 + kk1) * 32000));
          sa0 = cohL(ws + O_AVT + (long long)(kc + 2) * 2048 + tid);
          sa1 = cohL(ws + O_AVT + (long long)(kc + 2) * 2048 + 1024 + tid);
        }
        for (int k = 0; k < 64; ++k) {
          float w = wc[k * 128 + jl];
          float4 a = *(const float4*)(sav + k * 32 + b0);
          acc[0] += a.x * w; acc[1] += a.y * w; acc[2] += a.z * w; acc[3] += a.w * w;
        }
        ldsbar();
        // --- odd chunk (B regs) ---
        *(f4v*)(wc + kk0 * 128 + c4) = pb0;
        *(f4v*)(wc + kk1 * 128 + c4) = pb1;
        sav[tid] = sb0; sav[1024 + tid] = sb1;
        ldsbar();
        if (kc + 3 < 16) {
          pb0 = __builtin_nontemporal_load((const f4v*)(wsrc + (long long)((kc + 3) * 64 + kk0) * 32000));
          pb1 = __builtin_nontemporal_load((const f4v*)(wsrc + (long long)((kc + 3) * 64 + kk1) * 32000));
          sb0 = cohL(ws + O_AVT + (long long)(kc + 3) * 2048 + tid);
          sb1 = cohL(ws + O_AVT + (long long)(kc + 3) * 2048 + 1024 + tid);
        }
        for (int k = 0; k < 64; ++k) {
          float w = wc[k * 128 + jl];
          float4 a = *(const float4*)(sav + k * 32 + b0);
          acc[0] += a.x * w; acc[1] += a.y * w; acc[2] += a.z * w; acc[3] += a.w * w;
        }
        ldsbar();
      }
      float cb = clsB[j];
      float pvv[4];
      #pragma unroll
      for (int i = 0; i < 4; ++i) {
        pvv[i] = acc[i] + cb;
        __builtin_nontemporal_store(pvv[i], &out[((long long)s * 32 + b0 + i) * 32000 + j]);
      }
      float* lv = smem;
      int*   li = (int*)(smem + 4096);
      __syncthreads();
      #pragma unroll
      for (int i = 0; i < 4; ++i) {
        lv[(b0 + i) * 128 + jl] = pvv[i];
        li[(b0 + i) * 128 + jl] = j;
      }
      __syncthreads();
      float* l2v = smem + 8192;
      int*   l2i = (int*)(smem + 9216);
      {
        int b = tid >> 5, r = tid & 31;
        float bv = -3.4e38f; int bi2 = 0;
        #pragma unroll
        for (int i = 0; i < 4; ++i) {
          float v = lv[b * 128 + r + (i << 5)];
          int ix = li[b * 128 + r + (i << 5)];
          if (v > bv || (v == bv && ix < bi2)) { bv = v; bi2 = ix; }
        }
        l2v[b * 32 + r] = bv; l2i[b * 32 + r] = bi2;
      }
      __syncthreads();
      if (tid < 32) {
        float bv = -3.4e38f; int bi2 = 0;
        for (int r = 0; r < 32; ++r) {
          float v = l2v[tid * 32 + r]; int ix = l2i[tid * 32 + r];
          if (v > bv || (v == bv && ix < bi2)) { bv = v; bi2 = ix; }
        }
        ws[O_PARGV + bid * 32 + tid] = bv;
        ((int*)(ws + O_PARGI))[bid * 32 + tid] = bi2;
      }
      sigp(cnt + SUB_DD + (bid & 15) * 32, tid);
    }
  }
}

extern "C" void kernel_launch(void* const* d_in, const int* in_sizes, int n_in,
                              void* d_out, int out_size, void* d_ws, size_t ws_size,
                              hipStream_t stream) {
  const int*   inp    = (const int*)  d_in[0];
  const float* encEmb = (const float*)d_in[1];
  const float* encWih = (const float*)d_in[2];
  const float* encWhh = (const float*)d_in[3];
  const float* encBih = (const float*)d_in[4];
  const float* encBhh = (const float*)d_in[5];
  const float* decEmb = (const float*)d_in[6];
  const float* decWih = (const float*)d_in[7];
  const float* decWhh = (const float*)d_in[8];
  const float* decBih = (const float*)d_in[9];
  const float* decBhh = (const float*)d_in[10];
  const float* attnW  = (const float*)d_in[11];
  const float* attnB  = (const float*)d_in[12];
  const float* clsW   = (const float*)d_in[13];
  const float* clsB   = (const float*)d_in[14];
  float* out = (float*)d_out;
  float* ws  = (float*)d_ws;

  if (ws_size < (size_t)WS_FLOATS * sizeof(float)) return;

  // zero counters each launch (graph memset node, ordered before kernel)
  (void)hipMemsetAsync(ws + O_CNT, 0, 2560 * sizeof(int), stream);

  void* args[] = { &inp, &encEmb, &encWih, &encWhh, &encBih, &encBhh,
                   &decEmb, &decWih, &decWhh, &decBih, &decBhh,
                   &attnW, &attnB, &clsW, &clsB, &out, &ws };
  (void)hipLaunchCooperativeKernel((void*)seq2seq_kernel, dim3(NBLK), dim3(NTHR),
                                   args, 0, stream);
}

// Round 14
// 38617.184 us; speedup vs baseline: 3.0124x; 1.0265x over previous
//
#include <hip/hip_runtime.h>
#include <hip/hip_cooperative_groups.h>
#include <math.h>

namespace cg = cooperative_groups;

#define NBLK 256
#define NTHR 1024
#define AG  __HIP_MEMORY_SCOPE_AGENT
#define SYS __HIP_MEMORY_SCOPE_SYSTEM

typedef float f4v __attribute__((ext_vector_type(4)));

// Problem sizes
constexpr int Bc = 32, Tc = 128, Ec = 512, Hc = 1024, Ac = 1024, Vc = 32000, Sc = 100;
constexpr long long OUT_ATTN = (long long)Sc * Bc * Vc;

// ---- workspace layout (floats) ----
constexpr long long O_ENCWIH = 0;
constexpr long long O_ENCWHH = O_ENCWIH + (long long)512 * 3072;
constexpr long long O_DECWIH = O_ENCWHH + (long long)1024 * 3072;
constexpr long long O_DECWHH = O_DECWIH + (long long)1536 * 3072;
constexpr long long O_ATTNWT = O_DECWHH + (long long)1024 * 3072;
constexpr long long O_CLSWT  = O_ATTNWT + (long long)2048 * 1024;
constexpr long long O_XENCT  = O_CLSWT + (long long)1024 * 32000;
constexpr long long O_GI     = O_XENCT + (long long)128 * 512 * 32;
constexpr long long O_ENCOUT = O_GI + (long long)128 * 32 * 3072;
constexpr long long O_H0     = O_ENCOUT + (long long)32 * 128 * 1024;  // enc h ping
constexpr long long O_H1     = O_H0 + 32768;                           // enc h pong
constexpr long long O_H2     = O_H1 + 32768;                           // decoder h
constexpr long long O_AVT    = O_H2 + 32768;                           // av^T
constexpr long long O_CTXT   = O_AVT + 32768;                          // context^T
constexpr long long O_PADEC  = O_CTXT + 32768;                         // [10][32][4096]
constexpr long long O_PAENC  = O_PADEC + (long long)10 * 32 * 4096;    // [8][32][3072]
constexpr long long O_PAC    = O_PAENC + (long long)8 * 32 * 3072;     // [16][32][1024]
constexpr long long O_PARGV  = O_PAC + (long long)16 * 32 * 1024;      // [250][32]
constexpr long long O_PARGI  = O_PARGV + 8000;                         // [250][32] int
constexpr long long O_CNT    = O_PARGI + 8000;                         // int[2560] counters
constexpr long long WS_FLOATS = O_CNT + 2560;

// counter lines (int offsets; one 128B line each, 32-int spacing)
#define CI_H    128
#define CI_ENC  160   // + jc*32, jc<8   (160..383)
#define CI_DC   480   // + jc*32, jc<16  (480..959)
#define SUB_DA  1024  // + (bid&15)*32   16 lines, 15 arrivals each
#define SUB_DB  1536  // + (bid&7)*32     8 lines,  4 arrivals each
#define SUB_FIN 1792  // + (jc&7)*32      8 lines,  2 arrivals each
#define SUB_DD  2048  // + (bid&15)*32   16 lines, 16/15 arrivals each

// sc0sc1 (cache-bypassing, coherence-point) accessors for mutable cross-block data.
__device__ __forceinline__ float cohL(const float* p) { return __hip_atomic_load(p, __ATOMIC_RELAXED, SYS); }
__device__ __forceinline__ int   cohLi(const int* p) { return __hip_atomic_load(p, __ATOMIC_RELAXED, SYS); }
__device__ __forceinline__ void  cohS(float* p, float v) { __hip_atomic_store(p, v, __ATOMIC_RELAXED, SYS); }
__device__ __forceinline__ void  cohSi(int* p, int v) { __hip_atomic_store(p, v, __ATOMIC_RELAXED, SYS); }

// Single-line consumer spin (encoder; r9-proven protocol, backed-off poll rate).
__device__ __forceinline__ void spinw(int* c, int tgt, int tid) {
  if (tid == 0) {
    while (__hip_atomic_load(c, __ATOMIC_RELAXED, AG) < tgt)
      __builtin_amdgcn_s_sleep(32);
  }
  __syncthreads();
}
// Producer arrival (r9-proven): stores ack'd -> tid0 release fence (wbl2, no inv) -> RMW.
__device__ __forceinline__ void sigp(int* line, int tid) {
  __syncthreads();
  if (tid == 0) {
    __builtin_amdgcn_fence(__ATOMIC_RELEASE, "agent");
    atomicAdd(line, 1);
  }
}
// Spread-line consumer: threads 0..n-1 each poll a distinct 128B line.
template <int SLP>
__device__ __forceinline__ void pollsub(const int* base, int n, int tgt, int tid) {
  if (tid < n) {
    while (__hip_atomic_load(base + tid * 32, __ATOMIC_RELAXED, AG) < tgt)
      __builtin_amdgcn_s_sleep(SLP);
  }
  __syncthreads();
}
// LDS-only barrier: drain ds ops, rendezvous — global loads STAY IN FLIGHT.
__device__ __forceinline__ void ldsbar() {
  asm volatile("s_waitcnt lgkmcnt(0)" ::: "memory");
  __builtin_amdgcn_s_barrier();
}

__global__ __launch_bounds__(NTHR, 4) void seq2seq_kernel(
    const int* __restrict__ inp, const float* __restrict__ encEmb,
    const float* __restrict__ encWih, const float* __restrict__ encWhh,
    const float* __restrict__ encBih, const float* __restrict__ encBhh,
    const float* __restrict__ decEmb, const float* __restrict__ decWih,
    const float* __restrict__ decWhh, const float* __restrict__ decBih,
    const float* __restrict__ decBhh, const float* __restrict__ attnW,
    const float* __restrict__ attnB, const float* __restrict__ clsW,
    const float* __restrict__ clsB, float* __restrict__ out,
    float* __restrict__ ws)
{
  cg::grid_group grid = cg::this_grid();
  const int bid = blockIdx.x, tid = threadIdx.x;
  const long long gtid = (long long)bid * NTHR + tid;
  int* cnt = (int*)(ws + O_CNT);

  __shared__ float smem[10624];
  int* sflag = (int*)(smem + 10600);
  int* nids  = (int*)(smem + 10368);

  // ======================= P0: transposes + gathers + zeros =======================
  {
    const int sg = tid >> 8, st = tid & 255;
    float* tile = smem + sg * 1056;
    const int c = st & 31, rr = st >> 5;
    for (int it = 0; it < 46; ++it) {
      int job = it * (NBLK * 4) + bid * 4 + sg;
      const float* src = nullptr; float* dst = nullptr;
      int R = 0, C = 0, tr = 0, tcd = 0;
      bool valid = true;
      int j = job;
      if (j < 1536)               { src = encWih; dst = ws + O_ENCWIH; R = 3072;  C = 512;  tr = j >> 4; tcd = j & 15; }
      else if ((j -= 1536) < 3072){ src = encWhh; dst = ws + O_ENCWHH; R = 3072;  C = 1024; tr = j >> 5; tcd = j & 31; }
      else if ((j -= 3072) < 4608){ src = decWih; dst = ws + O_DECWIH; R = 3072;  C = 1536; tr = j / 48; tcd = j % 48; }
      else if ((j -= 4608) < 3072){ src = decWhh; dst = ws + O_DECWHH; R = 3072;  C = 1024; tr = j >> 5; tcd = j & 31; }
      else if ((j -= 3072) < 2048){ src = attnW;  dst = ws + O_ATTNWT; R = 1024;  C = 2048; tr = j >> 6; tcd = j & 63; }
      else if ((j -= 2048) < 32000){src = clsW;   dst = ws + O_CLSWT;  R = 32000; C = 1024; tr = j >> 5; tcd = j & 31; }
      else valid = false;
      if (valid) {
        #pragma unroll
        for (int i = 0; i < 4; ++i) {
          int r = rr + (i << 3);
          tile[r * 33 + c] = src[(long long)(tr * 32 + r) * C + tcd * 32 + c];
        }
      }
      __syncthreads();
      if (valid) {
        #pragma unroll
        for (int i = 0; i < 4; ++i) {
          int c2 = rr + (i << 3);
          dst[(long long)(tcd * 32 + c2) * R + tr * 32 + c] = tile[c * 33 + c2];
        }
      }
      __syncthreads();
    }
  }
  for (long long i = gtid; i < (long long)128 * 512 * 32; i += (long long)NBLK * NTHR) {
    int b = (int)(i & 31);
    int k = (int)((i >> 5) & 511);
    int t = (int)(i >> 14);
    int row = inp[b * Tc + t];
    ws[O_XENCT + i] = encEmb[(long long)row * Ec + k];
  }
  for (long long i = gtid; i < 32768; i += (long long)NBLK * NTHR) {
    ws[O_H0 + i] = 0.f;
    ws[O_AVT + i] = 0.f;
  }
  grid.sync();

  // ======================= P1: Gi =======================
  for (int it = 0; it < 6; ++it) {
    int job = it * NBLK + bid;
    int t = job / 12, jc = job % 12;
    int jl = tid & 255, bq = tid >> 8;
    int j = jc * 256 + jl;
    float acc[8] = {0,0,0,0,0,0,0,0};
    const float* xb = ws + O_XENCT + (long long)t * 512 * 32 + bq * 8;
    const float* wb = ws + O_ENCWIH + j;
    for (int k = 0; k < 512; ++k) {
      float w = wb[(long long)k * 3072];
      float4 x0 = *(const float4*)(xb + k * 32);
      float4 x1 = *(const float4*)(xb + k * 32 + 4);
      acc[0] += x0.x * w; acc[1] += x0.y * w; acc[2] += x0.z * w; acc[3] += x0.w * w;
      acc[4] += x1.x * w; acc[5] += x1.y * w; acc[6] += x1.z * w; acc[7] += x1.w * w;
    }
    float bias = encBih[j];
    #pragma unroll
    for (int i = 0; i < 8; ++i) {
      int b = bq * 8 + i;
      __builtin_nontemporal_store(acc[i] + bias, &ws[O_GI + ((long long)t * 32 + b) * 3072 + j]);
    }
  }
  grid.sync();

  // ======================= P2: encoder GRU (r13 structure; sc-stored partials) =======================
  if (bid < 192) {
    int g = bid / 64, rem = bid % 64;
    int jc = rem >> 3, kp = rem & 7;
    for (int t = 0; t < Tc; ++t) {
      long long RD = (t & 1) ? O_H1 : O_H0;
      long long WR = (t & 1) ? O_H0 : O_H1;
      spinw(cnt + CI_H, 8 * t, tid);
      {
        const float* hsrc = ws + RD + kp * 4096;
        #pragma unroll
        for (int r = 0; r < 4; ++r)
          smem[r * 1024 + tid] = cohL(hsrc + r * 1024 + tid);
      }
      __syncthreads();
      int jl = tid & 127, bq = tid >> 7;
      int col = g * 1024 + jc * 128 + jl;
      int b0 = bq * 4;
      float acc[4] = {0,0,0,0};
      const float* hb = smem + b0;
      const float* wb = ws + O_ENCWHH + (long long)(kp * 128) * 3072 + col;
      for (int k = 0; k < 128; ++k) {
        float w = wb[(long long)k * 3072];
        float4 x = *(const float4*)(hb + k * 32);
        acc[0] += x.x * w; acc[1] += x.y * w; acc[2] += x.z * w; acc[3] += x.w * w;
      }
      #pragma unroll
      for (int i = 0; i < 4; ++i)
        cohS(&ws[O_PAENC + ((long long)(kp * 32) + b0 + i) * 3072 + col], acc[i]);
      __syncthreads();
      if (tid == 0) {
        __builtin_amdgcn_fence(__ATOMIC_RELEASE, "agent");
        int old = atomicAdd(cnt + CI_ENC + jc * 32, 1);
        *sflag = (old == 24 * (t + 1) - 1) ? 1 : 0;
      }
      __syncthreads();
      if (*sflag) {
        int fj = tid & 127, fq = tid >> 7;
        int j = jc * 128 + fj;
        #pragma unroll
        for (int i = 0; i < 4; ++i) {
          int b = fq * 4 + i;
          float gr = 0, gz = 0, gn = 0;
          #pragma unroll
          for (int kp2 = 0; kp2 < 8; ++kp2) {
            long long base = O_PAENC + ((long long)(kp2 * 32) + b) * 3072;
            gr += cohL(&ws[base + j]);
            gz += cohL(&ws[base + 1024 + j]);
            gn += cohL(&ws[base + 2048 + j]);
          }
          long long gib = O_GI + ((long long)t * 32 + b) * 3072;
          float gir = ws[gib + j], giz = ws[gib + 1024 + j], gin = ws[gib + 2048 + j];
          float r = 1.f / (1.f + expf(-(gir + gr + encBhh[j])));
          float z = 1.f / (1.f + expf(-(giz + gz + encBhh[1024 + j])));
          float n = tanhf(gin + r * (gn + encBhh[2048 + j]));
          float hold = cohL(&ws[RD + (long long)j * 32 + b]);
          float hn = (1.f - z) * n + z * hold;
          ws[WR + (long long)j * 32 + b] = hn;
          ws[O_ENCOUT + ((long long)b * 128 + t) * 1024 + j] = hn;
          if (t == Tc - 1) ws[O_H2 + (long long)j * 32 + b] = hn;
        }
        sigp(cnt + CI_H, tid);
      }
      __syncthreads();
    }
  }

  // ======================= P3: decoder, spread-line dataflow =======================
  for (int s = 0; s < Sc; ++s) {
    // ---- DA (240 blocks) ----
    if (bid < 240) {
      int gate, loc;
      if (bid < 80)       { gate = 0; loc = bid; }
      else if (bid < 160) { gate = 1; loc = bid - 80; }
      else if (bid < 208) { gate = 2; loc = bid - 160; }
      else                { gate = 3; loc = bid - 208; }
      int nkp = (gate < 2) ? 10 : ((gate == 2) ? 6 : 4);
      int jc = loc / nkp, kp = loc % nkp;
      int kg = (gate == 3 ? 1536 : 0) + kp * 256;
      bool embp = (kg < 512);
      if (s == 0) {
        spinw(cnt + CI_H, 8 * Tc, tid); // encoder fully done
        if (tid < 32) nids[tid] = 0;
        __syncthreads();
      } else if (embp) {
        // wait DD(s-1): 16 spread lines, line i has (i<10?16:15) arrivals/step
        if (tid < 16) {
          int tgt = ((tid < 10) ? 16 : 15) * s;
          while (__hip_atomic_load(cnt + SUB_DD + tid * 32, __ATOMIC_RELAXED, AG) < tgt)
            __builtin_amdgcn_s_sleep(16);
        }
        __syncthreads();
        // argmax over 250 partials via coh reads (semilattice: order-free)
        float* pv = smem; int* pi = (int*)(smem + 1024);
        int b = tid & 31, ch = tid >> 5;
        float bv = -3.4e38f; int bi = 0;
        for (int r = ch; r < 250; r += 32) {
          float v = cohL(&ws[O_PARGV + r * 32 + b]);
          int ix = cohLi(((int*)(ws + O_PARGI)) + r * 32 + b);
          if (v > bv || (v == bv && ix < bi)) { bv = v; bi = ix; }
        }
        pv[ch * 32 + b] = bv; pi[ch * 32 + b] = bi;
        __syncthreads();
        if (tid < 32) {
          float bb = -3.4e38f; int bbi = 0;
          for (int c2 = 0; c2 < 32; ++c2) {
            float v = pv[c2 * 32 + tid]; int ix = pi[c2 * 32 + tid];
            if (v > bb || (v == bb && ix < bbi)) { bb = v; bbi = ix; }
          }
          nids[tid] = bbi;
        }
        __syncthreads();
      } else if (kg >= 1536) {
        pollsub<32>(cnt + SUB_DB, 8, 4 * s, tid);   // h2(s-1) ready
      } else {
        pollsub<32>(cnt + SUB_FIN, 8, 2 * s, tid);  // av(s-1) ready
      }
      // DA body (verbatim r9)
      int jl = tid & 127, bq = tid >> 7;
      int b0 = bq * 4;
      int jcol = jc * 128 + jl;
      int wcol = (gate >= 2 ? 2048 : gate * 1024) + jcol;
      const float* wb = (kg < 1536) ? (ws + O_DECWIH + (long long)kg * 3072 + wcol)
                                    : (ws + O_DECWHH + (long long)(kg - 1536) * 3072 + wcol);
      float acc[4] = {0,0,0,0};
      if (embp) {
        const float* e0 = decEmb + (long long)nids[b0    ] * 512 + kg;
        const float* e1 = decEmb + (long long)nids[b0 + 1] * 512 + kg;
        const float* e2 = decEmb + (long long)nids[b0 + 2] * 512 + kg;
        const float* e3 = decEmb + (long long)nids[b0 + 3] * 512 + kg;
        for (int k = 0; k < 256; ++k) {
          float w = wb[(long long)k * 3072];
          acc[0] += e0[k] * w; acc[1] += e1[k] * w; acc[2] += e2[k] * w; acc[3] += e3[k] * w;
        }
      } else {
        const float* src = (kg < 1536) ? (ws + O_AVT + (long long)(kg - 512) * 32)
                                       : (ws + O_H2 + (long long)(kg - 1536) * 32);
        #pragma unroll
        for (int r = 0; r < 8; ++r)
          smem[r * 1024 + tid] = cohL(src + r * 1024 + tid);
        __syncthreads();
        const float* xb = smem + b0;
        for (int k = 0; k < 256; ++k) {
          float w = wb[(long long)k * 3072];
          float4 x = *(const float4*)(xb + k * 32);
          acc[0] += x.x * w; acc[1] += x.y * w; acc[2] += x.z * w; acc[3] += x.w * w;
        }
      }
      int colout = gate * 1024 + jcol;
      #pragma unroll
      for (int i = 0; i < 4; ++i)
        cohS(&ws[O_PADEC + ((long long)(kp * 32) + b0 + i) * 4096 + colout], acc[i]);
      sigp(cnt + SUB_DA + (bid & 15) * 32, tid);
    }

    // ---- DB: gates finalize + attention + context (32 blocks) ----
    if (bid < 32) {
      pollsub<8>(cnt + SUB_DA, 16, 15 * (s + 1), tid);
      int b = bid;
      float* h2l = smem;
      float* scl = smem + 1024;
      float* wl  = smem + 1152;
      float* red = smem + 1280;
      {
        int j = tid;
        float gr = 0, gz = 0, gin = 0, ghn = 0;
        #pragma unroll
        for (int kp = 0; kp < 10; ++kp) {
          long long base = O_PADEC + ((long long)(kp * 32) + b) * 4096;
          gr += cohL(&ws[base + j]);
          gz += cohL(&ws[base + 1024 + j]);
          if (kp < 6) gin += cohL(&ws[base + 2048 + j]);
          if (kp < 4) ghn += cohL(&ws[base + 3072 + j]);
        }
        float r = 1.f / (1.f + expf(-(gr + decBih[j] + decBhh[j])));
        float z = 1.f / (1.f + expf(-(gz + decBih[1024 + j] + decBhh[1024 + j])));
        float n = tanhf(gin + decBih[2048 + j] + r * (ghn + decBhh[2048 + j]));
        float hold = ws[O_H2 + (long long)j * 32 + b]; // own bytes
        float h2 = (1.f - z) * n + z * hold;
        ws[O_H2 + (long long)j * 32 + b] = h2;
        h2l[j] = h2;
      }
      __syncthreads();
      { // scores
        int wv = tid >> 6, lane = tid & 63;
        float h2v[16];
        #pragma unroll
        for (int i = 0; i < 16; ++i) h2v[i] = h2l[lane + (i << 6)];
        for (int t8 = 0; t8 < 8; ++t8) {
          int tt = wv * 8 + t8;
          const float* eo = ws + O_ENCOUT + ((long long)b * 128 + tt) * 1024 + lane;
          float a = 0;
          #pragma unroll
          for (int i = 0; i < 16; ++i) a += eo[i << 6] * h2v[i];
          #pragma unroll
          for (int off = 32; off; off >>= 1) a += __shfl_xor(a, off, 64);
          if (lane == 0) scl[tt] = a;
        }
      }
      __syncthreads();
      { // softmax over 128
        float v = 0, m = -3.4e38f;
        if (tid < 128) {
          v = scl[tid]; m = v;
          #pragma unroll
          for (int off = 32; off; off >>= 1) m = fmaxf(m, __shfl_xor(m, off, 64));
          if ((tid & 63) == 0) red[tid >> 6] = m;
        }
        __syncthreads();
        float mm = fmaxf(red[0], red[1]);
        float e = 0.f;
        if (tid < 128) {
          e = expf(v - mm);
          float se = e;
          #pragma unroll
          for (int off = 32; off; off >>= 1) se += __shfl_xor(se, off, 64);
          if ((tid & 63) == 0) red[2 + (tid >> 6)] = se;
        }
        __syncthreads();
        if (tid < 128) {
          float wgt = e / (red[2] + red[3]);
          wl[tid] = wgt;
          __builtin_nontemporal_store(wgt, &out[OUT_ATTN + ((long long)s * 32 + b) * 128 + tid]);
        }
      }
      __syncthreads();
      { // context
        int j = tid;
        float a = 0;
        const float* eo = ws + O_ENCOUT + (long long)b * 128 * 1024 + j;
        for (int tt = 0; tt < 128; ++tt) a += wl[tt] * eo[(long long)tt * 1024];
        ws[O_CTXT + (long long)j * 32 + b] = a;
      }
      sigp(cnt + SUB_DB + (bid & 7) * 32, tid);
    }

    // ---- DC: av partials (all 256 blocks) + last-arriver DCfin (r13 structure) ----
    {
      pollsub<32>(cnt + SUB_DB, 8, 4 * (s + 1), tid);
      int jc = bid >> 4, kp = bid & 15;
      int kk0 = kp * 128;
      {
        const float* src = (kk0 < 1024) ? (ws + O_CTXT + (long long)kk0 * 32)
                                        : (ws + O_H2 + (long long)(kk0 - 1024) * 32);
        #pragma unroll
        for (int r = 0; r < 4; ++r)
          smem[r * 1024 + tid] = cohL(src + r * 1024 + tid);
      }
      __syncthreads();
      int jl = tid & 63, bh = tid >> 6;
      int b0 = bh * 2;
      int j = jc * 64 + jl;
      float acc0 = 0, acc1 = 0;
      const float* wb = ws + O_ATTNWT + (long long)kk0 * 1024 + j;
      const float* xb = smem + b0;
      for (int k = 0; k < 128; ++k) {
        float w = wb[(long long)k * 1024];
        float2 x = *(const float2*)(xb + k * 32);
        acc0 += x.x * w; acc1 += x.y * w;
      }
      cohS(&ws[O_PAC + ((long long)(kp * 32) + b0) * 1024 + j], acc0);
      cohS(&ws[O_PAC + ((long long)(kp * 32) + b0 + 1) * 1024 + j], acc1);
      __syncthreads();
      if (tid == 0) {
        __builtin_amdgcn_fence(__ATOMIC_RELEASE, "agent");
        int old = atomicAdd(cnt + CI_DC + jc * 32, 1);
        *sflag = (old == 16 * (s + 1) - 1) ? 1 : 0;
      }
      __syncthreads();
      if (*sflag) { // last arriver: DCfin for this jc (exact kp order)
        #pragma unroll
        for (int o = 0; o < 2; ++o) {
          int oo = tid + o * 1024;
          int j2 = jc * 64 + (oo >> 5), b = oo & 31;
          float sum = 0;
          #pragma unroll
          for (int kp2 = 0; kp2 < 16; ++kp2)
            sum += cohL(&ws[O_PAC + ((long long)(kp2 * 32) + b) * 1024 + j2]);
          ws[O_AVT + (long long)j2 * 32 + b] = tanhf(sum + attnB[j2]);
        }
        sigp(cnt + SUB_FIN + (jc & 7) * 32, tid);
      }
      __syncthreads();
    }

    // ---- DD: classifier + argmax partials (250 blocks; 2-deep prefetched NT clsW) ----
    if (bid < 250) {
      pollsub<32>(cnt + SUB_FIN, 8, 2 * (s + 1), tid);
      float* wc  = smem;        // [64][128] staged cls weights
      float* sav = smem + 8192; // [64][32] staged av chunk
      const int jl = tid & 127, bg = tid >> 7;
      const int b0 = bg * 4;
      const int j = bid * 128 + jl;
      const int kk0 = tid >> 5, kk1 = 32 + (tid >> 5);
      const int c4 = (tid & 31) * 4;
      const float* wsrc = ws + O_CLSWT + bid * 128 + c4;
      float acc[4] = {0,0,0,0};
      f4v pa0, pa1, pb0, pb1;
      float sa0, sa1, sb0, sb1;
      // prologue: issue chunks 0 (A) and 1 (B); stay in flight across ldsbar()
      pa0 = __builtin_nontemporal_load((const f4v*)(wsrc + (long long)(kk0) * 32000));
      pa1 = __builtin_nontemporal_load((const f4v*)(wsrc + (long long)(kk1) * 32000));
      sa0 = cohL(ws + O_AVT + tid);
      sa1 = cohL(ws + O_AVT + 1024 + tid);
      pb0 = __builtin_nontemporal_load((const f4v*)(wsrc + (long long)(64 + kk0) * 32000));
      pb1 = __builtin_nontemporal_load((const f4v*)(wsrc + (long long)(64 + kk1) * 32000));
      sb0 = cohL(ws + O_AVT + 2048 + tid);
      sb1 = cohL(ws + O_AVT + 2048 + 1024 + tid);
      #pragma unroll 1
      for (int kc = 0; kc < 16; kc += 2) {
        // --- even chunk (A regs) ---
        *(f4v*)(wc + kk0 * 128 + c4) = pa0;
        *(f4v*)(wc + kk1 * 128 + c4) = pa1;
        sav[tid] = sa0; sav[1024 + tid] = sa1;
        ldsbar();
        if (kc + 2 < 16) {
          pa0 = __builtin_nontemporal_load((const f4v*)(wsrc + (long long)((kc + 2) * 64 + kk0) * 32000));
          pa1 = __builtin_nontemporal_load((const f4v*)(wsrc + (long long)((kc + 2) * 64 + kk1) * 32000));
          sa0 = cohL(ws + O_AVT + (long long)(kc + 2) * 2048 + tid);
          sa1 = cohL(ws + O_AVT + (long long)(kc + 2) * 2048 + 1024 + tid);
        }
        for (int k = 0; k < 64; ++k) {
          float w = wc[k * 128 + jl];
          float4 a = *(const float4*)(sav + k * 32 + b0);
          acc[0] += a.x * w; acc[1] += a.y * w; acc[2] += a.z * w; acc[3] += a.w * w;
        }
        ldsbar();
        // --- odd chunk (B regs) ---
        *(f4v*)(wc + kk0 * 128 + c4) = pb0;
        *(f4v*)(wc + kk1 * 128 + c4) = pb1;
        sav[tid] = sb0; sav[1024 + tid] = sb1;
        ldsbar();
        if (kc + 3 < 16) {
          pb0 = __builtin_nontemporal_load((const f4v*)(wsrc + (long long)((kc + 3) * 64 + kk0) * 32000));
          pb1 = __builtin_nontemporal_load((const f4v*)(wsrc + (long long)((kc + 3) * 64 + kk1) * 32000));
          sb0 = cohL(ws + O_AVT + (long long)(kc + 3) * 2048 + tid);
          sb1 = cohL(ws + O_AVT + (long long)(kc + 3) * 2048 + 1024 + tid);
        }
        for (int k = 0; k < 64; ++k) {
          float w = wc[k * 128 + jl];
          float4 a = *(const float4*)(sav + k * 32 + b0);
          acc[0] += a.x * w; acc[1] += a.y * w; acc[2] += a.z * w; acc[3] += a.w * w;
        }
        ldsbar();
      }
      float cb = clsB[j];
      float pvv[4];
      #pragma unroll
      for (int i = 0; i < 4; ++i) {
        pvv[i] = acc[i] + cb;
        __builtin_nontemporal_store(pvv[i], &out[((long long)s * 32 + b0 + i) * 32000 + j]);
      }
      float* lv = smem;
      int*   li = (int*)(smem + 4096);
      __syncthreads();
      #pragma unroll
      for (int i = 0; i < 4; ++i) {
        lv[(b0 + i) * 128 + jl] = pvv[i];
        li[(b0 + i) * 128 + jl] = j;
      }
      __syncthreads();
      float* l2v = smem + 8192;
      int*   l2i = (int*)(smem + 9216);
      {
        int b = tid >> 5, r = tid & 31;
        float bv = -3.4e38f; int bi2 = 0;
        #pragma unroll
        for (int i = 0; i < 4; ++i) {
          float v = lv[b * 128 + r + (i << 5)];
          int ix = li[b * 128 + r + (i << 5)];
          if (v > bv || (v == bv && ix < bi2)) { bv = v; bi2 = ix; }
        }
        l2v[b * 32 + r] = bv; l2i[b * 32 + r] = bi2;
      }
      __syncthreads();
      if (tid < 32) {
        float bv = -3.4e38f; int bi2 = 0;
        for (int r = 0; r < 32; ++r) {
          float v = l2v[tid * 32 + r]; int ix = l2i[tid * 32 + r];
          if (v > bv || (v == bv && ix < bi2)) { bv = v; bi2 = ix; }
        }
        cohS(&ws[O_PARGV + bid * 32 + tid], bv);
        cohSi(((int*)(ws + O_PARGI)) + bid * 32 + tid, bi2);
      }
      sigp(cnt + SUB_DD + (bid & 15) * 32, tid);
    }
  }
}

extern "C" void kernel_launch(void* const* d_in, const int* in_sizes, int n_in,
                              void* d_out, int out_size, void* d_ws, size_t ws_size,
                              hipStream_t stream) {
  const int*   inp    = (const int*)  d_in[0];
  const float* encEmb = (const float*)d_in[1];
  const float* encWih = (const float*)d_in[2];
  const float* encWhh = (const float*)d_in[3];
  const float* encBih = (const float*)d_in[4];
  const float* encBhh = (const float*)d_in[5];
  const float* decEmb = (const float*)d_in[6];
  const float* decWih = (const float*)d_in[7];
  const float* decWhh = (const float*)d_in[8];
  const float* decBih = (const float*)d_in[9];
  const float* decBhh = (const float*)d_in[10];
  const float* attnW  = (const float*)d_in[11];
  const float* attnB  = (const float*)d_in[12];
  const float* clsW   = (const float*)d_in[13];
  const float* clsB   = (const float*)d_in[14];
  float* out = (float*)d_out;
  float* ws  = (float*)d_ws;

  if (ws_size < (size_t)WS_FLOATS * sizeof(float)) return;

  // zero counters each launch (graph memset node, ordered before kernel)
  (void)hipMemsetAsync(ws + O_CNT, 0, 2560 * sizeof(int), stream);

  void* args[] = { &inp, &encEmb, &encWih, &encWhh, &encBih, &encBhh,
                   &decEmb, &decWih, &decWhh, &decBih, &decBhh,
                   &attnW, &attnB, &clsW, &clsB, &out, &ws };
  (void)hipLaunchCooperativeKernel((void*)seq2seq_kernel, dim3(NBLK), dim3(NTHR),
                                   args, 0, stream);
}